// Round 5
// baseline (399.550 us; speedup 1.0000x reference)
//
#include <hip/hip_runtime.h>
#include <stdint.h>

typedef __attribute__((ext_vector_type(8))) short short8;
typedef __attribute__((ext_vector_type(4))) float f32x4;

// ---- problem constants ----
#define TOKENS 4096
#define DDIM 1024
#define IDIM 512
#define NEXP 16
#define NEXP1 17
#define NSLOTS 12288  // 4096 shared + 2*4096 routed

// ---- workspace layout (bytes) ----
#define OFF_WGU   0ull           // 17*1024*1024*2 = 35651584   [e][n(0..1023: g|u)][k] bf16
#define OFF_WD    35651584ull    // 17*1024*512*2  = 17825792   [e][n(D)][k(I)] bf16
#define OFF_XB    53477376ull    // 4096*1024*2    = 8388608    x in bf16
#define OFF_HGU   61865984ull    // 12288*1024*2   = 25165824   gemmA output
#define OFF_H     87031808ull    // 12288*512*2    = 12582912   silu(g)*u
#define OFF_TOK   99614720ull    // 17*4096*4      = 278528
#define OFF_WT    99893248ull    // 17*4096*4      = 278528
#define OFF_CNT   100171776ull   // 17*4 (+pad)
#define OFF_BASE  100172032ull   // 18*4

__device__ __forceinline__ float bf2f(unsigned short u) {
    union { uint32_t i; float f; } v; v.i = ((uint32_t)u) << 16; return v.f;
}
__device__ __forceinline__ unsigned short f2bf(float f) {
    union { float f; uint32_t i; } v; v.f = f;
    uint32_t r = v.i + 0x7FFFu + ((v.i >> 16) & 1u);  // RNE
    return (unsigned short)(r >> 16);
}

// ---- weight transpose + fp32->bf16: dst[n][k] k-contiguous ----
__global__ void k_transpose(const float* __restrict__ eg, const float* __restrict__ eu,
                            const float* __restrict__ ed, const float* __restrict__ sg,
                            const float* __restrict__ su, const float* __restrict__ sd,
                            unsigned short* __restrict__ Wgu, unsigned short* __restrict__ Wd)
{
    int z = blockIdx.z;
    int e = z / 3, m = z % 3;
    int R = (m == 2) ? 512 : 1024;   // src rows (k)
    int C = (m == 2) ? 1024 : 512;   // src cols (n)
    int r0 = blockIdx.y * 32, c0 = blockIdx.x * 32;
    if (r0 >= R || c0 >= C) return;
    const float* src;
    if (m == 0)      src = (e < 16) ? eg + (size_t)e * 524288 : sg;
    else if (m == 1) src = (e < 16) ? eu + (size_t)e * 524288 : su;
    else             src = (e < 16) ? ed + (size_t)e * 524288 : sd;

    __shared__ float tl[32][33];
    int c = threadIdx.x & 31, r = threadIdx.x >> 5;
    #pragma unroll
    for (int rr = 0; rr < 4; ++rr)
        tl[r + rr * 8][c] = src[(size_t)(r0 + r + rr * 8) * C + (c0 + c)];
    __syncthreads();
    #pragma unroll
    for (int rr = 0; rr < 4; ++rr) {
        int n = c0 + r + rr * 8;
        int k = r0 + c;
        unsigned short hv = f2bf(tl[c][r + rr * 8]);
        if (m < 2) Wgu[(size_t)e * 1048576 + (size_t)(n + (m == 1 ? 512 : 0)) * 1024 + k] = hv;
        else       Wd [(size_t)e * 524288  + (size_t)n * 512 + k] = hv;
    }
}

// ---- x -> bf16, out = x, fill shared-expert token list ----
__global__ void k_xconv(const float* __restrict__ x, unsigned short* __restrict__ xb,
                        float* __restrict__ out, int* __restrict__ tok, float* __restrict__ wt)
{
    int i = blockIdx.x * 256 + threadIdx.x;   // 1048576 float4 groups, exact
    float4 v = ((const float4*)x)[i];
    ((float4*)out)[i] = v;
    ushort4 b;
    b.x = f2bf(v.x); b.y = f2bf(v.y); b.z = f2bf(v.z); b.w = f2bf(v.w);
    ((ushort4*)xb)[i] = b;
    if (i < TOKENS) { tok[16 * 4096 + i] = i; wt[16 * 4096 + i] = 1.0f; }
}

// ---- router: expert-phased. LDS holds gw[k=0..1023][8 experts] per phase
//      (rows padded to 12 floats -> 48B stride, 16B-aligned, conflict-free b128).
//      Lane live set: xv[16] fp32 + 8 fp64 accs -> no spills. fp64 math kept. ----
__global__ __launch_bounds__(512, 4)
void k_router(const float* __restrict__ x, const float* __restrict__ gw,
              const float* __restrict__ gb, int* __restrict__ tok,
              float* __restrict__ wt, int* __restrict__ counts)
{
    __shared__ float gws[1024 * 12];             // 49152 B

    const int t = blockIdx.x * 8 + (threadIdx.x >> 6);   // 512 blocks * 8 waves
    const int lane = threadIdx.x & 63;
    const float* xr = x + (size_t)t * DDIM;

    float xv[16];
    #pragma unroll
    for (int kk = 0; kk < 16; ++kk) xv[kk] = xr[kk * 64 + lane];

    float v[16];

    for (int p = 0; p < 2; ++p) {
        __syncthreads();
        // stage gw[:, p*8 .. p*8+7]: 2048 float4, coalesced-ish, aligned b128 writes
        #pragma unroll
        for (int c = 0; c < 4; ++c) {
            int idx = threadIdx.x + c * 512;     // 0..2047
            int k = idx >> 1;
            int h = (idx & 1) * 4;               // 0 or 4 floats
            float4 g4 = *(const float4*)(gw + k * 16 + p * 8 + h);
            *(float4*)&gws[k * 12 + h] = g4;
        }
        __syncthreads();

        double a[8];
        #pragma unroll
        for (int j = 0; j < 8; ++j) a[j] = 0.0;

        #pragma unroll
        for (int kk = 0; kk < 16; ++kk) {
            int kl = kk * 64 + lane;
            float4 gA = *(const float4*)&gws[kl * 12];
            float4 gB = *(const float4*)&gws[kl * 12 + 4];
            double xd = (double)xv[kk];
            a[0] += xd * (double)gA.x; a[1] += xd * (double)gA.y;
            a[2] += xd * (double)gA.z; a[3] += xd * (double)gA.w;
            a[4] += xd * (double)gB.x; a[5] += xd * (double)gB.y;
            a[6] += xd * (double)gB.z; a[7] += xd * (double)gB.w;
        }

        #pragma unroll
        for (int off = 32; off > 0; off >>= 1) {
            #pragma unroll
            for (int j = 0; j < 8; ++j)
                a[j] += __shfl_xor(a[j], off, 64);
        }

        #pragma unroll
        for (int j = 0; j < 8; ++j)
            v[p * 8 + j] = 1.0f / (1.0f + expf(-(float)(a[j] + (double)gb[p * 8 + j])));
    }

    if (lane == 0) {
        int i0 = 0;
        #pragma unroll
        for (int e = 1; e < 16; ++e) if (v[e] > v[i0]) i0 = e;
        int i1 = (i0 == 0) ? 1 : 0;
        #pragma unroll
        for (int e = 0; e < 16; ++e) if (e != i0 && e != i1 && v[e] > v[i1]) i1 = e;
        float s = v[i0] + v[i1];
        float w0 = v[i0] / s, w1 = v[i1] / s;
        int p0 = atomicAdd(&counts[i0], 1);
        tok[i0 * 4096 + p0] = t; wt[i0 * 4096 + p0] = w0;
        int p1 = atomicAdd(&counts[i1], 1);
        tok[i1 * 4096 + p1] = t; wt[i1 * 4096 + p1] = w1;
    }
}

__global__ void k_prefix(int* counts, int* bases)
{
    if (threadIdx.x == 0 && blockIdx.x == 0) {
        counts[16] = TOKENS;
        int a = 0;
        for (int e = 0; e < NEXP1; ++e) { bases[e] = a; a += counts[e]; }
        bases[17] = a;
    }
}

// ---- grouped GEMM, 128x128 tile, 16x16x32 bf16 MFMA, 4 waves ----
// MODE 0: A = xb gathered by token_list, K=1024, B=Wgu, write Hgu (bf16)
// MODE 1: A = H (contiguous slots),     K=512,  B=Wd,  weighted atomicAdd into out
template <int MODE>
__global__ __launch_bounds__(256, 2)
void k_gemm(const unsigned short* __restrict__ Amat, const unsigned short* __restrict__ Bmat,
            const int* __restrict__ tok, const float* __restrict__ wt,
            const int* __restrict__ counts, const int* __restrict__ bases,
            unsigned short* __restrict__ Hgu, float* __restrict__ out)
{
    constexpr int K = (MODE == 0) ? 1024 : 512;
    const int e = blockIdx.z;
    const int cnt = counts[e];
    const int m0 = blockIdx.y * 128;
    if (m0 >= cnt) return;
    const int n0 = blockIdx.x * 128;
    const int base = bases[e];

    __shared__ unsigned short As[128 * 40];   // padded stride 40 -> 2-way (free) on frag reads
    __shared__ unsigned short Bs[128 * 40];

    const int tid = threadIdx.x;
    const int seg = tid & 3;      // 16B segment within 32-elem k-slab
    const int hrow = tid >> 2;    // 0..63

    const unsigned short* aptr[2];
    const unsigned short* bptr[2];
    unsigned short* asd[2];
    unsigned short* bsd[2];
    #pragma unroll
    for (int it = 0; it < 2; ++it) {
        int row = hrow + it * 64;
        int rc = m0 + row; if (rc > cnt - 1) rc = cnt - 1;
        size_t rowidx;
        if (MODE == 0) rowidx = (size_t)tok[e * 4096 + rc];
        else           rowidx = (size_t)(base + rc);
        aptr[it] = Amat + rowidx * K + seg * 8;
        bptr[it] = Bmat + (size_t)e * 1024 * K + (size_t)(n0 + row) * K + seg * 8;
        asd[it] = &As[row * 40 + seg * 8];
        bsd[it] = &Bs[row * 40 + seg * 8];
    }

    const int wave = tid >> 6;
    const int lane = tid & 63;
    const int wm = wave & 1, wn = wave >> 1;
    const int q = lane >> 4, mc = lane & 15;

    f32x4 acc[4][4];
    #pragma unroll
    for (int i = 0; i < 4; ++i)
        #pragma unroll
        for (int j = 0; j < 4; ++j) acc[i][j] = (f32x4){0.f, 0.f, 0.f, 0.f};

    for (int k0 = 0; k0 < K; k0 += 32) {
        uint4 av0 = *(const uint4*)(aptr[0] + k0);
        uint4 av1 = *(const uint4*)(aptr[1] + k0);
        uint4 bv0 = *(const uint4*)(bptr[0] + k0);
        uint4 bv1 = *(const uint4*)(bptr[1] + k0);
        __syncthreads();
        *(uint4*)asd[0] = av0;
        *(uint4*)asd[1] = av1;
        *(uint4*)bsd[0] = bv0;
        *(uint4*)bsd[1] = bv1;
        __syncthreads();
        short8 a[4], b[4];
        #pragma unroll
        for (int i = 0; i < 4; ++i)
            a[i] = *(const short8*)&As[(wm * 64 + i * 16 + mc) * 40 + q * 8];
        #pragma unroll
        for (int j = 0; j < 4; ++j)
            b[j] = *(const short8*)&Bs[(wn * 64 + j * 16 + mc) * 40 + q * 8];
        #pragma unroll
        for (int i = 0; i < 4; ++i)
            #pragma unroll
            for (int j = 0; j < 4; ++j)
                acc[i][j] = __builtin_amdgcn_mfma_f32_16x16x32_bf16(a[i], b[j], acc[i][j], 0, 0, 0);
    }

    // epilogue: C/D layout col=lane&15, row=(lane>>4)*4+reg  [m89-verified]
    #pragma unroll
    for (int i = 0; i < 4; ++i) {
        int lrow = wm * 64 + i * 16 + q * 4;
        #pragma unroll
        for (int r = 0; r < 4; ++r) {
            int mrow = m0 + lrow + r;
            if (mrow >= cnt) continue;
            if (MODE == 0) {
                size_t rowoff = (size_t)(base + mrow) * 1024;
                #pragma unroll
                for (int j = 0; j < 4; ++j) {
                    int gc = n0 + wn * 64 + j * 16 + mc;
                    Hgu[rowoff + gc] = f2bf(acc[i][j][r]);
                }
            } else {
                int t = tok[e * 4096 + mrow];
                float w = wt[e * 4096 + mrow];
                size_t rowoff = (size_t)t * 1024;
                #pragma unroll
                for (int j = 0; j < 4; ++j) {
                    int gc = n0 + wn * 64 + j * 16 + mc;
                    atomicAdd(&out[rowoff + gc], w * acc[i][j][r]);
                }
            }
        }
    }
}

// ---- H[s][i] = silu(Hgu[s][i]) * Hgu[s][i+512] ----
__global__ void k_silu(const unsigned short* __restrict__ Hgu, unsigned short* __restrict__ H)
{
    int gid = blockIdx.x * 256 + threadIdx.x;  // 786432 threads, exact
    int s = gid >> 6;
    int c = (gid & 63) * 8;
    const unsigned short* g = Hgu + (size_t)s * 1024 + c;
    unsigned short gg[8], uu[8], oo[8];
    *(uint4*)gg = *(const uint4*)g;
    *(uint4*)uu = *(const uint4*)(g + 512);
    #pragma unroll
    for (int j = 0; j < 8; ++j) {
        float gv = bf2f(gg[j]);
        float uv = bf2f(uu[j]);
        float sv = gv / (1.0f + __expf(-gv));
        oo[j] = f2bf(sv * uv);
    }
    *(uint4*)(H + (size_t)s * 512 + c) = *(uint4*)oo;
}

extern "C" void kernel_launch(void* const* d_in, const int* in_sizes, int n_in,
                              void* d_out, int out_size, void* d_ws, size_t ws_size,
                              hipStream_t stream)
{
    const float* x  = (const float*)d_in[0];
    const float* gw = (const float*)d_in[1];
    const float* gb = (const float*)d_in[2];
    const float* sg = (const float*)d_in[3];
    const float* su = (const float*)d_in[4];
    const float* sd = (const float*)d_in[5];
    const float* eg = (const float*)d_in[6];
    const float* eu = (const float*)d_in[7];
    const float* ed = (const float*)d_in[8];
    float* out = (float*)d_out;
    char* ws = (char*)d_ws;

    unsigned short* Wgu = (unsigned short*)(ws + OFF_WGU);
    unsigned short* Wd  = (unsigned short*)(ws + OFF_WD);
    unsigned short* xb  = (unsigned short*)(ws + OFF_XB);
    unsigned short* Hgu = (unsigned short*)(ws + OFF_HGU);
    unsigned short* H   = (unsigned short*)(ws + OFF_H);
    int*   tok   = (int*)(ws + OFF_TOK);
    float* wt    = (float*)(ws + OFF_WT);
    int*   counts= (int*)(ws + OFF_CNT);
    int*   bases = (int*)(ws + OFF_BASE);

    hipMemsetAsync(counts, 0, 128, stream);
    k_transpose<<<dim3(32, 32, 51), 256, 0, stream>>>(eg, eu, ed, sg, su, sd, Wgu, Wd);
    k_xconv<<<4096, 256, 0, stream>>>(x, xb, out, tok, wt);
    k_router<<<512, 512, 0, stream>>>(x, gw, gb, tok, wt, counts);
    k_prefix<<<1, 64, 0, stream>>>(counts, bases);
    k_gemm<0><<<dim3(8, 32, 17), 256, 0, stream>>>(xb, Wgu, tok, wt, counts, bases, Hgu, out);
    k_silu<<<3072, 256, 0, stream>>>(Hgu, H);
    k_gemm<1><<<dim3(8, 32, 17), 256, 0, stream>>>(H, Wd, tok, wt, counts, bases, Hgu, out);
}

// Round 6
// 319.329 us; speedup vs baseline: 1.2512x; 1.2512x over previous
//
#include <hip/hip_runtime.h>
#include <stdint.h>

typedef __attribute__((ext_vector_type(8))) short short8;
typedef __attribute__((ext_vector_type(4))) float f32x4;

// ---- problem constants ----
#define TOKENS 4096
#define DDIM 1024
#define IDIM 512
#define NEXP 16
#define NEXP1 17
#define NSLOTS 12288  // 4096 shared + 2*4096 routed
#define CSTRIDE 32    // counts padded: one counter per 128 B (atomic line ping-pong fix)

// ---- workspace layout (bytes) ----
#define OFF_WGU   0ull           // 17*1024*1024*2 = 35651584   [e][n(0..1023: g|u)][k] bf16
#define OFF_WD    35651584ull    // 17*1024*512*2  = 17825792   [e][n(D)][k(I)] bf16
#define OFF_XB    53477376ull    // 4096*1024*2    = 8388608    x in bf16
#define OFF_HGU   61865984ull    // 12288*1024*2   = 25165824   gemmA output
#define OFF_H     87031808ull    // 12288*512*2    = 12582912   silu(g)*u
#define OFF_TOK   99614720ull    // 17*4096*4      = 278528
#define OFF_WT    99893248ull    // 17*4096*4      = 278528
#define OFF_CNT   100171776ull   // 17*128 padded counters (4096 B reserved)
#define OFF_BASE  100175872ull   // 18*4

__device__ __forceinline__ float bf2f(unsigned short u) {
    union { uint32_t i; float f; } v; v.i = ((uint32_t)u) << 16; return v.f;
}
__device__ __forceinline__ unsigned short f2bf(float f) {
    union { float f; uint32_t i; } v; v.f = f;
    uint32_t r = v.i + 0x7FFFu + ((v.i >> 16) & 1u);  // RNE
    return (unsigned short)(r >> 16);
}

// ---- weight transpose + fp32->bf16: dst[n][k] k-contiguous ----
__global__ void k_transpose(const float* __restrict__ eg, const float* __restrict__ eu,
                            const float* __restrict__ ed, const float* __restrict__ sg,
                            const float* __restrict__ su, const float* __restrict__ sd,
                            unsigned short* __restrict__ Wgu, unsigned short* __restrict__ Wd)
{
    int z = blockIdx.z;
    int e = z / 3, m = z % 3;
    int R = (m == 2) ? 512 : 1024;   // src rows (k)
    int C = (m == 2) ? 1024 : 512;   // src cols (n)
    int r0 = blockIdx.y * 32, c0 = blockIdx.x * 32;
    if (r0 >= R || c0 >= C) return;
    const float* src;
    if (m == 0)      src = (e < 16) ? eg + (size_t)e * 524288 : sg;
    else if (m == 1) src = (e < 16) ? eu + (size_t)e * 524288 : su;
    else             src = (e < 16) ? ed + (size_t)e * 524288 : sd;

    __shared__ float tl[32][33];
    int c = threadIdx.x & 31, r = threadIdx.x >> 5;
    #pragma unroll
    for (int rr = 0; rr < 4; ++rr)
        tl[r + rr * 8][c] = src[(size_t)(r0 + r + rr * 8) * C + (c0 + c)];
    __syncthreads();
    #pragma unroll
    for (int rr = 0; rr < 4; ++rr) {
        int n = c0 + r + rr * 8;
        int k = r0 + c;
        unsigned short hv = f2bf(tl[c][r + rr * 8]);
        if (m < 2) Wgu[(size_t)e * 1048576 + (size_t)(n + (m == 1 ? 512 : 0)) * 1024 + k] = hv;
        else       Wd [(size_t)e * 524288  + (size_t)n * 512 + k] = hv;
    }
}

// ---- x -> bf16, out = x, fill shared-expert token list ----
__global__ void k_xconv(const float* __restrict__ x, unsigned short* __restrict__ xb,
                        float* __restrict__ out, int* __restrict__ tok, float* __restrict__ wt)
{
    int i = blockIdx.x * 256 + threadIdx.x;   // 1048576 float4 groups, exact
    float4 v = ((const float4*)x)[i];
    ((float4*)out)[i] = v;
    ushort4 b;
    b.x = f2bf(v.x); b.y = f2bf(v.y); b.z = f2bf(v.z); b.w = f2bf(v.w);
    ((ushort4*)xb)[i] = b;
    if (i < TOKENS) { tok[16 * 4096 + i] = i; wt[16 * 4096 + i] = 1.0f; }
}

// ---- router: expert-phased LDS staging, fp64 accumulate, padded atomics ----
__global__ __launch_bounds__(512, 4)
void k_router(const float* __restrict__ x, const float* __restrict__ gw,
              const float* __restrict__ gb, int* __restrict__ tok,
              float* __restrict__ wt, int* __restrict__ counts)
{
    __shared__ float gws[1024 * 12];             // 49152 B

    const int t = blockIdx.x * 8 + (threadIdx.x >> 6);   // 512 blocks * 8 waves
    const int lane = threadIdx.x & 63;
    const float* xr = x + (size_t)t * DDIM;

    float xv[16];
    #pragma unroll
    for (int kk = 0; kk < 16; ++kk) xv[kk] = xr[kk * 64 + lane];

    float v[16];

    for (int p = 0; p < 2; ++p) {
        __syncthreads();
        // stage gw[:, p*8 .. p*8+7]: 2048 float4, aligned b128 writes
        #pragma unroll
        for (int c = 0; c < 4; ++c) {
            int idx = threadIdx.x + c * 512;     // 0..2047
            int k = idx >> 1;
            int h = (idx & 1) * 4;               // 0 or 4 floats
            float4 g4 = *(const float4*)(gw + k * 16 + p * 8 + h);
            *(float4*)&gws[k * 12 + h] = g4;
        }
        __syncthreads();

        double a[8];
        #pragma unroll
        for (int j = 0; j < 8; ++j) a[j] = 0.0;

        #pragma unroll
        for (int kk = 0; kk < 16; ++kk) {
            int kl = kk * 64 + lane;
            float4 gA = *(const float4*)&gws[kl * 12];
            float4 gB = *(const float4*)&gws[kl * 12 + 4];
            double xd = (double)xv[kk];
            a[0] += xd * (double)gA.x; a[1] += xd * (double)gA.y;
            a[2] += xd * (double)gA.z; a[3] += xd * (double)gA.w;
            a[4] += xd * (double)gB.x; a[5] += xd * (double)gB.y;
            a[6] += xd * (double)gB.z; a[7] += xd * (double)gB.w;
        }

        #pragma unroll
        for (int off = 32; off > 0; off >>= 1) {
            #pragma unroll
            for (int j = 0; j < 8; ++j)
                a[j] += __shfl_xor(a[j], off, 64);
        }

        #pragma unroll
        for (int j = 0; j < 8; ++j)
            v[p * 8 + j] = 1.0f / (1.0f + expf(-(float)(a[j] + (double)gb[p * 8 + j])));
    }

    if (lane == 0) {
        int i0 = 0;
        #pragma unroll
        for (int e = 1; e < 16; ++e) if (v[e] > v[i0]) i0 = e;
        int i1 = (i0 == 0) ? 1 : 0;
        #pragma unroll
        for (int e = 0; e < 16; ++e) if (e != i0 && e != i1 && v[e] > v[i1]) i1 = e;
        float s = v[i0] + v[i1];
        float w0 = v[i0] / s, w1 = v[i1] / s;
        int p0 = atomicAdd(&counts[i0 * CSTRIDE], 1);   // padded: 1 line per expert
        tok[i0 * 4096 + p0] = t; wt[i0 * 4096 + p0] = w0;
        int p1 = atomicAdd(&counts[i1 * CSTRIDE], 1);
        tok[i1 * 4096 + p1] = t; wt[i1 * 4096 + p1] = w1;
    }
}

__global__ void k_prefix(int* counts, int* bases)
{
    if (threadIdx.x == 0 && blockIdx.x == 0) {
        counts[16 * CSTRIDE] = TOKENS;
        int a = 0;
        for (int e = 0; e < NEXP1; ++e) { bases[e] = a; a += counts[e * CSTRIDE]; }
        bases[17] = a;
    }
}

// ---- grouped GEMM, 128x128 tile, 16x16x32 bf16 MFMA, 4 waves ----
// MODE 0: A = xb gathered by token_list, K=1024, B=Wgu, write Hgu (bf16)
// MODE 1: A = H (contiguous slots),     K=512,  B=Wd,  weighted atomicAdd into out
template <int MODE>
__global__ __launch_bounds__(256, 2)
void k_gemm(const unsigned short* __restrict__ Amat, const unsigned short* __restrict__ Bmat,
            const int* __restrict__ tok, const float* __restrict__ wt,
            const int* __restrict__ counts, const int* __restrict__ bases,
            unsigned short* __restrict__ Hgu, float* __restrict__ out)
{
    constexpr int K = (MODE == 0) ? 1024 : 512;
    const int e = blockIdx.z;
    const int cnt = counts[e * CSTRIDE];
    const int m0 = blockIdx.y * 128;
    if (m0 >= cnt) return;
    const int n0 = blockIdx.x * 128;
    const int base = bases[e];

    __shared__ unsigned short As[128 * 40];   // padded stride 40 -> 2-way (free) on frag reads
    __shared__ unsigned short Bs[128 * 40];

    const int tid = threadIdx.x;
    const int seg = tid & 3;      // 16B segment within 32-elem k-slab
    const int hrow = tid >> 2;    // 0..63

    const unsigned short* aptr[2];
    const unsigned short* bptr[2];
    unsigned short* asd[2];
    unsigned short* bsd[2];
    #pragma unroll
    for (int it = 0; it < 2; ++it) {
        int row = hrow + it * 64;
        int rc = m0 + row; if (rc > cnt - 1) rc = cnt - 1;
        size_t rowidx;
        if (MODE == 0) rowidx = (size_t)tok[e * 4096 + rc];
        else           rowidx = (size_t)(base + rc);
        aptr[it] = Amat + rowidx * K + seg * 8;
        bptr[it] = Bmat + (size_t)e * 1024 * K + (size_t)(n0 + row) * K + seg * 8;
        asd[it] = &As[row * 40 + seg * 8];
        bsd[it] = &Bs[row * 40 + seg * 8];
    }

    const int wave = tid >> 6;
    const int lane = tid & 63;
    const int wm = wave & 1, wn = wave >> 1;
    const int q = lane >> 4, mc = lane & 15;

    f32x4 acc[4][4];
    #pragma unroll
    for (int i = 0; i < 4; ++i)
        #pragma unroll
        for (int j = 0; j < 4; ++j) acc[i][j] = (f32x4){0.f, 0.f, 0.f, 0.f};

    for (int k0 = 0; k0 < K; k0 += 32) {
        uint4 av0 = *(const uint4*)(aptr[0] + k0);
        uint4 av1 = *(const uint4*)(aptr[1] + k0);
        uint4 bv0 = *(const uint4*)(bptr[0] + k0);
        uint4 bv1 = *(const uint4*)(bptr[1] + k0);
        __syncthreads();
        *(uint4*)asd[0] = av0;
        *(uint4*)asd[1] = av1;
        *(uint4*)bsd[0] = bv0;
        *(uint4*)bsd[1] = bv1;
        __syncthreads();
        short8 a[4], b[4];
        #pragma unroll
        for (int i = 0; i < 4; ++i)
            a[i] = *(const short8*)&As[(wm * 64 + i * 16 + mc) * 40 + q * 8];
        #pragma unroll
        for (int j = 0; j < 4; ++j)
            b[j] = *(const short8*)&Bs[(wn * 64 + j * 16 + mc) * 40 + q * 8];
        #pragma unroll
        for (int i = 0; i < 4; ++i)
            #pragma unroll
            for (int j = 0; j < 4; ++j)
                acc[i][j] = __builtin_amdgcn_mfma_f32_16x16x32_bf16(a[i], b[j], acc[i][j], 0, 0, 0);
    }

    // epilogue: C/D layout col=lane&15, row=(lane>>4)*4+reg  [m89-verified]
    #pragma unroll
    for (int i = 0; i < 4; ++i) {
        int lrow = wm * 64 + i * 16 + q * 4;
        #pragma unroll
        for (int r = 0; r < 4; ++r) {
            int mrow = m0 + lrow + r;
            if (mrow >= cnt) continue;
            if (MODE == 0) {
                size_t rowoff = (size_t)(base + mrow) * 1024;
                #pragma unroll
                for (int j = 0; j < 4; ++j) {
                    int gc = n0 + wn * 64 + j * 16 + mc;
                    Hgu[rowoff + gc] = f2bf(acc[i][j][r]);
                }
            } else {
                int t = tok[e * 4096 + mrow];
                float w = wt[e * 4096 + mrow];
                size_t rowoff = (size_t)t * 1024;
                #pragma unroll
                for (int j = 0; j < 4; ++j) {
                    int gc = n0 + wn * 64 + j * 16 + mc;
                    atomicAdd(&out[rowoff + gc], w * acc[i][j][r]);
                }
            }
        }
    }
}

// ---- H[s][i] = silu(Hgu[s][i]) * Hgu[s][i+512] ----
__global__ void k_silu(const unsigned short* __restrict__ Hgu, unsigned short* __restrict__ H)
{
    int gid = blockIdx.x * 256 + threadIdx.x;  // 786432 threads, exact
    int s = gid >> 6;
    int c = (gid & 63) * 8;
    const unsigned short* g = Hgu + (size_t)s * 1024 + c;
    unsigned short gg[8], uu[8], oo[8];
    *(uint4*)gg = *(const uint4*)g;
    *(uint4*)uu = *(const uint4*)(g + 512);
    #pragma unroll
    for (int j = 0; j < 8; ++j) {
        float gv = bf2f(gg[j]);
        float uv = bf2f(uu[j]);
        float sv = gv / (1.0f + __expf(-gv));
        oo[j] = f2bf(sv * uv);
    }
    *(uint4*)(H + (size_t)s * 512 + c) = *(uint4*)oo;
}

extern "C" void kernel_launch(void* const* d_in, const int* in_sizes, int n_in,
                              void* d_out, int out_size, void* d_ws, size_t ws_size,
                              hipStream_t stream)
{
    const float* x  = (const float*)d_in[0];
    const float* gw = (const float*)d_in[1];
    const float* gb = (const float*)d_in[2];
    const float* sg = (const float*)d_in[3];
    const float* su = (const float*)d_in[4];
    const float* sd = (const float*)d_in[5];
    const float* eg = (const float*)d_in[6];
    const float* eu = (const float*)d_in[7];
    const float* ed = (const float*)d_in[8];
    float* out = (float*)d_out;
    char* ws = (char*)d_ws;

    unsigned short* Wgu = (unsigned short*)(ws + OFF_WGU);
    unsigned short* Wd  = (unsigned short*)(ws + OFF_WD);
    unsigned short* xb  = (unsigned short*)(ws + OFF_XB);
    unsigned short* Hgu = (unsigned short*)(ws + OFF_HGU);
    unsigned short* H   = (unsigned short*)(ws + OFF_H);
    int*   tok   = (int*)(ws + OFF_TOK);
    float* wt    = (float*)(ws + OFF_WT);
    int*   counts= (int*)(ws + OFF_CNT);
    int*   bases = (int*)(ws + OFF_BASE);

    hipMemsetAsync(counts, 0, 4096, stream);
    k_transpose<<<dim3(32, 32, 51), 256, 0, stream>>>(eg, eu, ed, sg, su, sd, Wgu, Wd);
    k_xconv<<<4096, 256, 0, stream>>>(x, xb, out, tok, wt);
    k_router<<<512, 512, 0, stream>>>(x, gw, gb, tok, wt, counts);
    k_prefix<<<1, 64, 0, stream>>>(counts, bases);
    k_gemm<0><<<dim3(8, 32, 17), 256, 0, stream>>>(xb, Wgu, tok, wt, counts, bases, Hgu, out);
    k_silu<<<3072, 256, 0, stream>>>(Hgu, H);
    k_gemm<1><<<dim3(8, 32, 17), 256, 0, stream>>>(H, Wd, tok, wt, counts, bases, Hgu, out);
}

// Round 7
// 293.151 us; speedup vs baseline: 1.3629x; 1.0893x over previous
//
#include <hip/hip_runtime.h>
#include <stdint.h>

typedef __attribute__((ext_vector_type(8))) short short8;
typedef __attribute__((ext_vector_type(4))) float f32x4;

// ---- problem constants ----
#define TOKENS 4096
#define DDIM 1024
#define IDIM 512
#define NEXP 16
#define NEXP1 17
#define CSTRIDE 32    // counts padded: one counter per 128 B (atomic line ping-pong fix)

// ---- workspace layout (bytes) ----
#define OFF_WGU   0ull           // 17*1024*1024*2 = 35651584   [e][n(0..1023: g|u)][k] bf16
#define OFF_WD    35651584ull    // 17*1024*512*2  = 17825792   [e][n(D)][k(I)] bf16
#define OFF_XB    53477376ull    // 4096*1024*2    = 8388608    x in bf16
#define OFF_HGU   61865984ull    // 12288*1024*2   = 25165824   gemmA out; REUSED as gemmB out
#define OFF_H     87031808ull    // 12288*512*2    = 12582912   silu(g)*u
#define OFF_TOK   99614720ull    // 17*4096*4      = 278528
#define OFF_REC   99893248ull    // 4096*8  per-token (e,p) records
#define OFF_WREC  99926016ull    // 4096*8  per-token (w0,w1)
#define OFF_CNT   100171776ull   // 17*128 padded counters (4096 B reserved)
#define OFF_BASE  100175872ull   // 18*4

__device__ __forceinline__ float bf2f(unsigned short u) {
    union { uint32_t i; float f; } v; v.i = ((uint32_t)u) << 16; return v.f;
}
__device__ __forceinline__ unsigned short f2bf(float f) {
    union { float f; uint32_t i; } v; v.f = f;
    uint32_t r = v.i + 0x7FFFu + ((v.i >> 16) & 1u);  // RNE
    return (unsigned short)(r >> 16);
}
// async 16B global->LDS (dest = wave-uniform base + lane*16)
__device__ __forceinline__ void cp16(const unsigned short* g, unsigned short* l) {
    __builtin_amdgcn_global_load_lds(
        (const __attribute__((address_space(1))) uint32_t*)g,
        (__attribute__((address_space(3))) uint32_t*)l, 16, 0, 0);
}

// ---- weight transpose + fp32->bf16: dst[n][k] k-contiguous ----
__global__ void k_transpose(const float* __restrict__ eg, const float* __restrict__ eu,
                            const float* __restrict__ ed, const float* __restrict__ sg,
                            const float* __restrict__ su, const float* __restrict__ sd,
                            unsigned short* __restrict__ Wgu, unsigned short* __restrict__ Wd)
{
    int z = blockIdx.z;
    int e = z / 3, m = z % 3;
    int R = (m == 2) ? 512 : 1024;   // src rows (k)
    int C = (m == 2) ? 1024 : 512;   // src cols (n)
    int r0 = blockIdx.y * 32, c0 = blockIdx.x * 32;
    if (r0 >= R || c0 >= C) return;
    const float* src;
    if (m == 0)      src = (e < 16) ? eg + (size_t)e * 524288 : sg;
    else if (m == 1) src = (e < 16) ? eu + (size_t)e * 524288 : su;
    else             src = (e < 16) ? ed + (size_t)e * 524288 : sd;

    __shared__ float tl[32][33];
    int c = threadIdx.x & 31, r = threadIdx.x >> 5;
    #pragma unroll
    for (int rr = 0; rr < 4; ++rr)
        tl[r + rr * 8][c] = src[(size_t)(r0 + r + rr * 8) * C + (c0 + c)];
    __syncthreads();
    #pragma unroll
    for (int rr = 0; rr < 4; ++rr) {
        int n = c0 + r + rr * 8;
        int k = r0 + c;
        unsigned short hv = f2bf(tl[c][r + rr * 8]);
        if (m < 2) Wgu[(size_t)e * 1048576 + (size_t)(n + (m == 1 ? 512 : 0)) * 1024 + k] = hv;
        else       Wd [(size_t)e * 524288  + (size_t)n * 512 + k] = hv;
    }
}

// ---- x -> bf16, fill shared-expert token list ----
__global__ void k_xconv(const float* __restrict__ x, unsigned short* __restrict__ xb,
                        int* __restrict__ tok)
{
    int i = blockIdx.x * 256 + threadIdx.x;   // 1048576 float4 groups, exact
    float4 v = ((const float4*)x)[i];
    ushort4 b;
    b.x = f2bf(v.x); b.y = f2bf(v.y); b.z = f2bf(v.z); b.w = f2bf(v.w);
    ((ushort4*)xb)[i] = b;
    if (i < TOKENS) tok[16 * 4096 + i] = i;
}

// ---- router: expert-phased LDS staging, fp64 accumulate, padded atomics ----
__global__ __launch_bounds__(512, 4)
void k_router(const float* __restrict__ x, const float* __restrict__ gw,
              const float* __restrict__ gb, int* __restrict__ tok,
              int2* __restrict__ rec, float2* __restrict__ wrec,
              int* __restrict__ counts)
{
    __shared__ float gws[1024 * 12];             // 49152 B

    const int t = blockIdx.x * 8 + (threadIdx.x >> 6);   // 512 blocks * 8 waves
    const int lane = threadIdx.x & 63;
    const float* xr = x + (size_t)t * DDIM;

    float xv[16];
    #pragma unroll
    for (int kk = 0; kk < 16; ++kk) xv[kk] = xr[kk * 64 + lane];

    float v[16];

    for (int p = 0; p < 2; ++p) {
        __syncthreads();
        #pragma unroll
        for (int c = 0; c < 4; ++c) {
            int idx = threadIdx.x + c * 512;     // 0..2047
            int k = idx >> 1;
            int h = (idx & 1) * 4;               // 0 or 4 floats
            float4 g4 = *(const float4*)(gw + k * 16 + p * 8 + h);
            *(float4*)&gws[k * 12 + h] = g4;
        }
        __syncthreads();

        double a[8];
        #pragma unroll
        for (int j = 0; j < 8; ++j) a[j] = 0.0;

        #pragma unroll
        for (int kk = 0; kk < 16; ++kk) {
            int kl = kk * 64 + lane;
            float4 gA = *(const float4*)&gws[kl * 12];
            float4 gB = *(const float4*)&gws[kl * 12 + 4];
            double xd = (double)xv[kk];
            a[0] += xd * (double)gA.x; a[1] += xd * (double)gA.y;
            a[2] += xd * (double)gA.z; a[3] += xd * (double)gA.w;
            a[4] += xd * (double)gB.x; a[5] += xd * (double)gB.y;
            a[6] += xd * (double)gB.z; a[7] += xd * (double)gB.w;
        }

        #pragma unroll
        for (int off = 32; off > 0; off >>= 1) {
            #pragma unroll
            for (int j = 0; j < 8; ++j)
                a[j] += __shfl_xor(a[j], off, 64);
        }

        #pragma unroll
        for (int j = 0; j < 8; ++j)
            v[p * 8 + j] = 1.0f / (1.0f + expf(-(float)(a[j] + (double)gb[p * 8 + j])));
    }

    if (lane == 0) {
        int i0 = 0;
        #pragma unroll
        for (int e = 1; e < 16; ++e) if (v[e] > v[i0]) i0 = e;
        int i1 = (i0 == 0) ? 1 : 0;
        #pragma unroll
        for (int e = 0; e < 16; ++e) if (e != i0 && e != i1 && v[e] > v[i1]) i1 = e;
        float s = v[i0] + v[i1];
        float w0 = v[i0] / s, w1 = v[i1] / s;
        int p0 = atomicAdd(&counts[i0 * CSTRIDE], 1);   // padded: 1 line per expert
        tok[i0 * 4096 + p0] = t;
        int p1 = atomicAdd(&counts[i1 * CSTRIDE], 1);
        tok[i1 * 4096 + p1] = t;
        rec[t]  = make_int2(i0 * 4096 + p0, i1 * 4096 + p1);
        wrec[t] = make_float2(w0, w1);
    }
}

__global__ void k_prefix(int* counts, int* bases)
{
    if (threadIdx.x == 0 && blockIdx.x == 0) {
        counts[16 * CSTRIDE] = TOKENS;
        int a = 0;
        for (int e = 0; e < NEXP1; ++e) { bases[e] = a; a += counts[e * CSTRIDE]; }
        bases[17] = a;
    }
}

// ---- grouped GEMM, 128x128 tile, 16x16x32 bf16 MFMA, 4 waves,
//      m97-style global_load_lds staging (unpadded stride-32 LDS) ----
// MODE 0: A = xb gathered by token_list, K=1024, B=Wgu -> Hgu slots (bf16)
// MODE 1: A = H  (contiguous slots),     K=512,  B=Wd  -> Hgu slots (bf16, unweighted)
template <int MODE>
__global__ __launch_bounds__(256, 3)
void k_gemm(const unsigned short* __restrict__ Amat, const unsigned short* __restrict__ Bmat,
            const int* __restrict__ tok, const int* __restrict__ counts,
            const int* __restrict__ bases, unsigned short* __restrict__ Hgu)
{
    constexpr int K = (MODE == 0) ? 1024 : 512;
    const int e = blockIdx.z;
    const int cnt = counts[e * CSTRIDE];
    const int m0 = blockIdx.y * 128;
    if (m0 >= cnt) return;
    const int n0 = blockIdx.x * 128;
    const int base = bases[e];

    __shared__ unsigned short As[128 * 32];   // 8 KB, unpadded (global_load_lds layout)
    __shared__ unsigned short Bs[128 * 32];

    const int tid  = threadIdx.x;
    const int wave = tid >> 6;
    const int lane = tid & 63;
    const int lrow = lane >> 2;     // 0..15
    const int lseg = lane & 3;      // 16B segment within 32-elem k-slab

    // wave-uniform LDS dests: each inst covers 16 rows (64 lanes * 16 B)
    unsigned short* a_dst0 = &As[wave * 1024];
    unsigned short* a_dst1 = &As[wave * 1024 + 512];
    unsigned short* b_dst0 = &Bs[wave * 1024];
    unsigned short* b_dst1 = &Bs[wave * 1024 + 512];

    // per-lane global source addresses (wave w stages rows w*32 .. w*32+31)
    int ar0 = m0 + wave * 32 + lrow;      if (ar0 > cnt - 1) ar0 = cnt - 1;
    int ar1 = m0 + wave * 32 + 16 + lrow; if (ar1 > cnt - 1) ar1 = cnt - 1;
    size_t ai0, ai1;
    if (MODE == 0) { ai0 = (size_t)tok[e * 4096 + ar0]; ai1 = (size_t)tok[e * 4096 + ar1]; }
    else           { ai0 = (size_t)(base + ar0);        ai1 = (size_t)(base + ar1); }
    const unsigned short* ag0 = Amat + ai0 * K + lseg * 8;
    const unsigned short* ag1 = Amat + ai1 * K + lseg * 8;
    const size_t eoff = (size_t)e * 1024 * K;
    const unsigned short* bg0 = Bmat + eoff + (size_t)(n0 + wave * 32 + lrow) * K + lseg * 8;
    const unsigned short* bg1 = Bmat + eoff + (size_t)(n0 + wave * 32 + 16 + lrow) * K + lseg * 8;

    const int wm = wave & 1, wn = wave >> 1;
    const int q = lane >> 4, mc = lane & 15;

    f32x4 acc[4][4];
    #pragma unroll
    for (int i = 0; i < 4; ++i)
        #pragma unroll
        for (int j = 0; j < 4; ++j) acc[i][j] = (f32x4){0.f, 0.f, 0.f, 0.f};

    for (int k0 = 0; k0 < K; k0 += 32) {
        __syncthreads();                       // prev iter's ds_reads done
        cp16(ag0 + k0, a_dst0);
        cp16(ag1 + k0, a_dst1);
        cp16(bg0 + k0, b_dst0);
        cp16(bg1 + k0, b_dst1);
        __syncthreads();                       // vmcnt(0) drain: staged data visible
        short8 a[4], b[4];
        #pragma unroll
        for (int i = 0; i < 4; ++i)
            a[i] = *(const short8*)&As[(wm * 64 + i * 16 + mc) * 32 + q * 8];
        #pragma unroll
        for (int j = 0; j < 4; ++j)
            b[j] = *(const short8*)&Bs[(wn * 64 + j * 16 + mc) * 32 + q * 8];
        #pragma unroll
        for (int i = 0; i < 4; ++i)
            #pragma unroll
            for (int j = 0; j < 4; ++j)
                acc[i][j] = __builtin_amdgcn_mfma_f32_16x16x32_bf16(a[i], b[j], acc[i][j], 0, 0, 0);
    }

    // epilogue: C/D layout col=lane&15, row=(lane>>4)*4+reg  [m89-verified]
    #pragma unroll
    for (int i = 0; i < 4; ++i) {
        int lr = wm * 64 + i * 16 + q * 4;
        #pragma unroll
        for (int r = 0; r < 4; ++r) {
            int mrow = m0 + lr + r;
            if (mrow >= cnt) continue;
            size_t rowoff = (size_t)(base + mrow) * 1024;
            #pragma unroll
            for (int j = 0; j < 4; ++j) {
                int gc = n0 + wn * 64 + j * 16 + mc;
                Hgu[rowoff + gc] = f2bf(acc[i][j][r]);
            }
        }
    }
}

// ---- H[s][i] = silu(Hgu[s][i]) * Hgu[s][i+512] ----
__global__ void k_silu(const unsigned short* __restrict__ Hgu, unsigned short* __restrict__ H)
{
    int gid = blockIdx.x * 256 + threadIdx.x;  // 786432 threads, exact
    int s = gid >> 6;
    int c = (gid & 63) * 8;
    const unsigned short* g = Hgu + (size_t)s * 1024 + c;
    unsigned short gg[8], uu[8], oo[8];
    *(uint4*)gg = *(const uint4*)g;
    *(uint4*)uu = *(const uint4*)(g + 512);
    #pragma unroll
    for (int j = 0; j < 8; ++j) {
        float gv = bf2f(gg[j]);
        float uv = bf2f(uu[j]);
        float sv = gv / (1.0f + __expf(-gv));
        oo[j] = f2bf(sv * uv);
    }
    *(uint4*)(H + (size_t)s * 512 + c) = *(uint4*)oo;
}

// ---- out[t] = x[t] + Hs[shared] + w0*Hs[s0] + w1*Hs[s1] ----
__global__ void k_combine(const float* __restrict__ x, const unsigned short* __restrict__ Hs,
                          const int2* __restrict__ rec, const float2* __restrict__ wrec,
                          const int* __restrict__ bases, float* __restrict__ out)
{
    int t = blockIdx.x * 2 + (threadIdx.x >> 7);   // 2048 blocks * 2 tokens
    int c = (threadIdx.x & 127) * 8;
    int2 r = rec[t];
    float2 w = wrec[t];
    int s0 = bases[r.x >> 12] + (r.x & 4095);
    int s1 = bases[r.y >> 12] + (r.y & 4095);
    int ss = 8192 + t;                              // shared list base is always 8192

    unsigned short h0[8], h1[8], hs[8];
    *(uint4*)h0 = *(const uint4*)(Hs + (size_t)s0 * 1024 + c);
    *(uint4*)h1 = *(const uint4*)(Hs + (size_t)s1 * 1024 + c);
    *(uint4*)hs = *(const uint4*)(Hs + (size_t)ss * 1024 + c);
    const float* xr = x + (size_t)t * 1024 + c;
    float o[8];
    #pragma unroll
    for (int j = 0; j < 8; ++j)
        o[j] = xr[j] + bf2f(hs[j]) + w.x * bf2f(h0[j]) + w.y * bf2f(h1[j]);
    float* orow = out + (size_t)t * 1024 + c;
    *(float4*)orow       = *(float4*)&o[0];
    *(float4*)(orow + 4) = *(float4*)&o[4];
}

extern "C" void kernel_launch(void* const* d_in, const int* in_sizes, int n_in,
                              void* d_out, int out_size, void* d_ws, size_t ws_size,
                              hipStream_t stream)
{
    const float* x  = (const float*)d_in[0];
    const float* gw = (const float*)d_in[1];
    const float* gb = (const float*)d_in[2];
    const float* sg = (const float*)d_in[3];
    const float* su = (const float*)d_in[4];
    const float* sd = (const float*)d_in[5];
    const float* eg = (const float*)d_in[6];
    const float* eu = (const float*)d_in[7];
    const float* ed = (const float*)d_in[8];
    float* out = (float*)d_out;
    char* ws = (char*)d_ws;

    unsigned short* Wgu = (unsigned short*)(ws + OFF_WGU);
    unsigned short* Wd  = (unsigned short*)(ws + OFF_WD);
    unsigned short* xb  = (unsigned short*)(ws + OFF_XB);
    unsigned short* Hgu = (unsigned short*)(ws + OFF_HGU);
    unsigned short* H   = (unsigned short*)(ws + OFF_H);
    int*    tok   = (int*)(ws + OFF_TOK);
    int2*   rec   = (int2*)(ws + OFF_REC);
    float2* wrec  = (float2*)(ws + OFF_WREC);
    int*    counts= (int*)(ws + OFF_CNT);
    int*    bases = (int*)(ws + OFF_BASE);

    hipMemsetAsync(counts, 0, 4096, stream);
    k_transpose<<<dim3(32, 32, 51), 256, 0, stream>>>(eg, eu, ed, sg, su, sd, Wgu, Wd);
    k_xconv<<<4096, 256, 0, stream>>>(x, xb, tok);
    k_router<<<512, 512, 0, stream>>>(x, gw, gb, tok, rec, wrec, counts);
    k_prefix<<<1, 64, 0, stream>>>(counts, bases);
    k_gemm<0><<<dim3(8, 32, 17), 256, 0, stream>>>(xb, Wgu, tok, counts, bases, Hgu);
    k_silu<<<3072, 256, 0, stream>>>(Hgu, H);
    k_gemm<1><<<dim3(8, 32, 17), 256, 0, stream>>>(H, Wd, tok, counts, bases, Hgu);
    k_combine<<<2048, 256, 0, stream>>>(x, Hgu, rec, wrec, bases, out);
}

// Round 8
// 292.703 us; speedup vs baseline: 1.3650x; 1.0015x over previous
//
#include <hip/hip_runtime.h>
#include <stdint.h>

typedef __attribute__((ext_vector_type(8))) short short8;
typedef __attribute__((ext_vector_type(4))) float f32x4;

// ---- problem constants ----
#define TOKENS 4096
#define DDIM 1024
#define IDIM 512
#define NEXP 16
#define NEXP1 17
#define CSTRIDE 32    // counts padded: one counter per 128 B (atomic line ping-pong fix)

// ---- workspace layout (bytes) ----
#define OFF_WGU   0ull           // 17*1024*1024*2 = 35651584   [e][n(0..1023: g|u)][k] bf16
#define OFF_WD    35651584ull    // 17*1024*512*2  = 17825792   [e][n(D)][k(I)] bf16
#define OFF_XB    53477376ull    // 4096*1024*2    = 8388608    x in bf16
#define OFF_HGU   61865984ull    // 12288*1024*2   = 25165824   gemmA out; REUSED as gemmB out
#define OFF_H     87031808ull    // 12288*512*2    = 12582912   silu(g)*u
#define OFF_TOK   99614720ull    // 17*4096*4      = 278528
#define OFF_REC   99893248ull    // 4096*8  per-token (e,p) records
#define OFF_WREC  99926016ull    // 4096*8  per-token (w0,w1)
#define OFF_CNT   100171776ull   // 17*128 padded counters (4096 B reserved)
#define OFF_BASE  100175872ull   // 18*4

__device__ __forceinline__ float bf2f(unsigned short u) {
    union { uint32_t i; float f; } v; v.i = ((uint32_t)u) << 16; return v.f;
}
__device__ __forceinline__ unsigned short f2bf(float f) {
    union { float f; uint32_t i; } v; v.f = f;
    uint32_t r = v.i + 0x7FFFu + ((v.i >> 16) & 1u);  // RNE
    return (unsigned short)(r >> 16);
}
// async 16B global->LDS (dest = wave-uniform base + lane*16)
__device__ __forceinline__ void cp16(const unsigned short* g, unsigned short* l) {
    __builtin_amdgcn_global_load_lds(
        (const __attribute__((address_space(1))) uint32_t*)g,
        (__attribute__((address_space(3))) uint32_t*)l, 16, 0, 0);
}

// ---- weight transpose + fp32->bf16: dst[n][k] k-contiguous.
//      64x64 tiles, 16 elem/thread: 4x float4 loads, LDS stride-65 (2-way = free),
//      2x uint4 stores (32B contiguous k per thread). ----
__global__ __launch_bounds__(256)
void k_transpose(const float* __restrict__ eg, const float* __restrict__ eu,
                 const float* __restrict__ ed, const float* __restrict__ sg,
                 const float* __restrict__ su, const float* __restrict__ sd,
                 unsigned short* __restrict__ Wgu, unsigned short* __restrict__ Wd)
{
    int z = blockIdx.z;
    int e = z / 3, m = z % 3;
    int R = (m == 2) ? 512 : 1024;   // src rows (k)
    int C = (m == 2) ? 1024 : 512;   // src cols (n)
    int r0 = blockIdx.y * 64, c0 = blockIdx.x * 64;
    if (r0 >= R || c0 >= C) return;
    const float* src;
    if (m == 0)      src = (e < 16) ? eg + (size_t)e * 524288 : sg;
    else if (m == 1) src = (e < 16) ? eu + (size_t)e * 524288 : su;
    else             src = (e < 16) ? ed + (size_t)e * 524288 : sd;

    __shared__ float tl[64 * 65];
    const int tid = threadIdx.x;

    // load: 4 passes, each: row = pass*16 + tid/16, col4 = tid%16 (float4)
    {
        const int lr = tid >> 4;          // 0..15
        const int lc = (tid & 15) * 4;    // 0..60
        #pragma unroll
        for (int ps = 0; ps < 4; ++ps) {
            int r = ps * 16 + lr;
            float4 v = *(const float4*)(src + (size_t)(r0 + r) * C + (c0 + lc));
            float* d = &tl[r * 65 + lc];
            d[0] = v.x; d[1] = v.y; d[2] = v.z; d[3] = v.w;
        }
    }
    __syncthreads();

    // store: thread -> n = c0 + (tid>>2), 16 consecutive k at (tid&3)*16
    {
        const int nl = tid >> 2;          // 0..63
        const int kc = (tid & 3) * 16;    // 0,16,32,48
        unsigned short ov[16];
        #pragma unroll
        for (int j = 0; j < 16; ++j)
            ov[j] = f2bf(tl[(kc + j) * 65 + nl]);
        int n = c0 + nl;
        int k = r0 + kc;
        unsigned short* dst;
        if (m < 2) dst = Wgu + (size_t)e * 1048576 + (size_t)(n + (m == 1 ? 512 : 0)) * 1024 + k;
        else       dst = Wd  + (size_t)e * 524288  + (size_t)n * 512 + k;
        *(uint4*)dst       = *(uint4*)&ov[0];
        *(uint4*)(dst + 8) = *(uint4*)&ov[8];
    }
}

// ---- x -> bf16, fill shared-expert token list ----
__global__ void k_xconv(const float* __restrict__ x, unsigned short* __restrict__ xb,
                        int* __restrict__ tok)
{
    int i = blockIdx.x * 256 + threadIdx.x;   // 1048576 float4 groups, exact
    float4 v = ((const float4*)x)[i];
    ushort4 b;
    b.x = f2bf(v.x); b.y = f2bf(v.y); b.z = f2bf(v.z); b.w = f2bf(v.w);
    ((ushort4*)xb)[i] = b;
    if (i < TOKENS) tok[16 * 4096 + i] = i;
}

// ---- router: expert-phased LDS staging, fp64 accumulate, padded atomics ----
__global__ __launch_bounds__(512, 4)
void k_router(const float* __restrict__ x, const float* __restrict__ gw,
              const float* __restrict__ gb, int* __restrict__ tok,
              int2* __restrict__ rec, float2* __restrict__ wrec,
              int* __restrict__ counts)
{
    __shared__ float gws[1024 * 12];             // 49152 B

    const int t = blockIdx.x * 8 + (threadIdx.x >> 6);   // 512 blocks * 8 waves
    const int lane = threadIdx.x & 63;
    const float* xr = x + (size_t)t * DDIM;

    float xv[16];
    #pragma unroll
    for (int kk = 0; kk < 16; ++kk) xv[kk] = xr[kk * 64 + lane];

    float v[16];

    for (int p = 0; p < 2; ++p) {
        __syncthreads();
        #pragma unroll
        for (int c = 0; c < 4; ++c) {
            int idx = threadIdx.x + c * 512;     // 0..2047
            int k = idx >> 1;
            int h = (idx & 1) * 4;               // 0 or 4 floats
            float4 g4 = *(const float4*)(gw + k * 16 + p * 8 + h);
            *(float4*)&gws[k * 12 + h] = g4;
        }
        __syncthreads();

        double a[8];
        #pragma unroll
        for (int j = 0; j < 8; ++j) a[j] = 0.0;

        #pragma unroll
        for (int kk = 0; kk < 16; ++kk) {
            int kl = kk * 64 + lane;
            float4 gA = *(const float4*)&gws[kl * 12];
            float4 gB = *(const float4*)&gws[kl * 12 + 4];
            double xd = (double)xv[kk];
            a[0] += xd * (double)gA.x; a[1] += xd * (double)gA.y;
            a[2] += xd * (double)gA.z; a[3] += xd * (double)gA.w;
            a[4] += xd * (double)gB.x; a[5] += xd * (double)gB.y;
            a[6] += xd * (double)gB.z; a[7] += xd * (double)gB.w;
        }

        #pragma unroll
        for (int off = 32; off > 0; off >>= 1) {
            #pragma unroll
            for (int j = 0; j < 8; ++j)
                a[j] += __shfl_xor(a[j], off, 64);
        }

        #pragma unroll
        for (int j = 0; j < 8; ++j)
            v[p * 8 + j] = 1.0f / (1.0f + expf(-(float)(a[j] + (double)gb[p * 8 + j])));
    }

    if (lane == 0) {
        int i0 = 0;
        #pragma unroll
        for (int e = 1; e < 16; ++e) if (v[e] > v[i0]) i0 = e;
        int i1 = (i0 == 0) ? 1 : 0;
        #pragma unroll
        for (int e = 0; e < 16; ++e) if (e != i0 && e != i1 && v[e] > v[i1]) i1 = e;
        float s = v[i0] + v[i1];
        float w0 = v[i0] / s, w1 = v[i1] / s;
        int p0 = atomicAdd(&counts[i0 * CSTRIDE], 1);   // padded: 1 line per expert
        tok[i0 * 4096 + p0] = t;
        int p1 = atomicAdd(&counts[i1 * CSTRIDE], 1);
        tok[i1 * 4096 + p1] = t;
        rec[t]  = make_int2(i0 * 4096 + p0, i1 * 4096 + p1);
        wrec[t] = make_float2(w0, w1);
    }
}

__global__ void k_prefix(int* counts, int* bases)
{
    if (threadIdx.x == 0 && blockIdx.x == 0) {
        counts[16 * CSTRIDE] = TOKENS;
        int a = 0;
        for (int e = 0; e < NEXP1; ++e) { bases[e] = a; a += counts[e * CSTRIDE]; }
        bases[17] = a;
    }
}

// ---- grouped GEMM, 128x128 tile, 16x16x32 bf16 MFMA, 4 waves,
//      m97-style global_load_lds staging (unpadded stride-32 LDS) ----
// MODE 0: A = xb gathered by token_list, K=1024, B=Wgu -> Hgu slots (bf16)
// MODE 1: A = H  (contiguous slots),     K=512,  B=Wd  -> Hgu slots (bf16, unweighted)
template <int MODE>
__global__ __launch_bounds__(256, 3)
void k_gemm(const unsigned short* __restrict__ Amat, const unsigned short* __restrict__ Bmat,
            const int* __restrict__ tok, const int* __restrict__ counts,
            const int* __restrict__ bases, unsigned short* __restrict__ Hgu)
{
    constexpr int K = (MODE == 0) ? 1024 : 512;
    const int e = blockIdx.z;
    const int cnt = counts[e * CSTRIDE];
    const int m0 = blockIdx.y * 128;
    if (m0 >= cnt) return;
    const int n0 = blockIdx.x * 128;
    const int base = bases[e];

    __shared__ unsigned short As[128 * 32];   // 8 KB, unpadded (global_load_lds layout)
    __shared__ unsigned short Bs[128 * 32];

    const int tid  = threadIdx.x;
    const int wave = tid >> 6;
    const int lane = tid & 63;
    const int lrow = lane >> 2;     // 0..15
    const int lseg = lane & 3;      // 16B segment within 32-elem k-slab

    // wave-uniform LDS dests: each inst covers 16 rows (64 lanes * 16 B)
    unsigned short* a_dst0 = &As[wave * 1024];
    unsigned short* a_dst1 = &As[wave * 1024 + 512];
    unsigned short* b_dst0 = &Bs[wave * 1024];
    unsigned short* b_dst1 = &Bs[wave * 1024 + 512];

    // per-lane global source addresses (wave w stages rows w*32 .. w*32+31)
    int ar0 = m0 + wave * 32 + lrow;      if (ar0 > cnt - 1) ar0 = cnt - 1;
    int ar1 = m0 + wave * 32 + 16 + lrow; if (ar1 > cnt - 1) ar1 = cnt - 1;
    size_t ai0, ai1;
    if (MODE == 0) { ai0 = (size_t)tok[e * 4096 + ar0]; ai1 = (size_t)tok[e * 4096 + ar1]; }
    else           { ai0 = (size_t)(base + ar0);        ai1 = (size_t)(base + ar1); }
    const unsigned short* ag0 = Amat + ai0 * K + lseg * 8;
    const unsigned short* ag1 = Amat + ai1 * K + lseg * 8;
    const size_t eoff = (size_t)e * 1024 * K;
    const unsigned short* bg0 = Bmat + eoff + (size_t)(n0 + wave * 32 + lrow) * K + lseg * 8;
    const unsigned short* bg1 = Bmat + eoff + (size_t)(n0 + wave * 32 + 16 + lrow) * K + lseg * 8;

    const int wm = wave & 1, wn = wave >> 1;
    const int q = lane >> 4, mc = lane & 15;

    f32x4 acc[4][4];
    #pragma unroll
    for (int i = 0; i < 4; ++i)
        #pragma unroll
        for (int j = 0; j < 4; ++j) acc[i][j] = (f32x4){0.f, 0.f, 0.f, 0.f};

    for (int k0 = 0; k0 < K; k0 += 32) {
        __syncthreads();                       // prev iter's ds_reads done
        cp16(ag0 + k0, a_dst0);
        cp16(ag1 + k0, a_dst1);
        cp16(bg0 + k0, b_dst0);
        cp16(bg1 + k0, b_dst1);
        __syncthreads();                       // vmcnt(0) drain: staged data visible
        short8 a[4], b[4];
        #pragma unroll
        for (int i = 0; i < 4; ++i)
            a[i] = *(const short8*)&As[(wm * 64 + i * 16 + mc) * 32 + q * 8];
        #pragma unroll
        for (int j = 0; j < 4; ++j)
            b[j] = *(const short8*)&Bs[(wn * 64 + j * 16 + mc) * 32 + q * 8];
        #pragma unroll
        for (int i = 0; i < 4; ++i)
            #pragma unroll
            for (int j = 0; j < 4; ++j)
                acc[i][j] = __builtin_amdgcn_mfma_f32_16x16x32_bf16(a[i], b[j], acc[i][j], 0, 0, 0);
    }

    // epilogue: C/D layout col=lane&15, row=(lane>>4)*4+reg  [m89-verified]
    #pragma unroll
    for (int i = 0; i < 4; ++i) {
        int lr = wm * 64 + i * 16 + q * 4;
        #pragma unroll
        for (int r = 0; r < 4; ++r) {
            int mrow = m0 + lr + r;
            if (mrow >= cnt) continue;
            size_t rowoff = (size_t)(base + mrow) * 1024;
            #pragma unroll
            for (int j = 0; j < 4; ++j) {
                int gc = n0 + wn * 64 + j * 16 + mc;
                Hgu[rowoff + gc] = f2bf(acc[i][j][r]);
            }
        }
    }
}

// ---- H[s][i] = silu(Hgu[s][i]) * Hgu[s][i+512] ----
__global__ void k_silu(const unsigned short* __restrict__ Hgu, unsigned short* __restrict__ H)
{
    int gid = blockIdx.x * 256 + threadIdx.x;  // 786432 threads, exact
    int s = gid >> 6;
    int c = (gid & 63) * 8;
    const unsigned short* g = Hgu + (size_t)s * 1024 + c;
    unsigned short gg[8], uu[8], oo[8];
    *(uint4*)gg = *(const uint4*)g;
    *(uint4*)uu = *(const uint4*)(g + 512);
    #pragma unroll
    for (int j = 0; j < 8; ++j) {
        float gv = bf2f(gg[j]);
        float uv = bf2f(uu[j]);
        float sv = gv / (1.0f + __expf(-gv));
        oo[j] = f2bf(sv * uv);
    }
    *(uint4*)(H + (size_t)s * 512 + c) = *(uint4*)oo;
}

// ---- out[t] = x[t] + Hs[shared] + w0*Hs[s0] + w1*Hs[s1] ----
__global__ void k_combine(const float* __restrict__ x, const unsigned short* __restrict__ Hs,
                          const int2* __restrict__ rec, const float2* __restrict__ wrec,
                          const int* __restrict__ bases, float* __restrict__ out)
{
    int t = blockIdx.x * 2 + (threadIdx.x >> 7);   // 2048 blocks * 2 tokens
    int c = (threadIdx.x & 127) * 8;
    int2 r = rec[t];
    float2 w = wrec[t];
    int s0 = bases[r.x >> 12] + (r.x & 4095);
    int s1 = bases[r.y >> 12] + (r.y & 4095);
    int ss = 8192 + t;                              // shared list base is always 8192

    unsigned short h0[8], h1[8], hs[8];
    *(uint4*)h0 = *(const uint4*)(Hs + (size_t)s0 * 1024 + c);
    *(uint4*)h1 = *(const uint4*)(Hs + (size_t)s1 * 1024 + c);
    *(uint4*)hs = *(const uint4*)(Hs + (size_t)ss * 1024 + c);
    const float* xr = x + (size_t)t * 1024 + c;
    float o[8];
    #pragma unroll
    for (int j = 0; j < 8; ++j)
        o[j] = xr[j] + bf2f(hs[j]) + w.x * bf2f(h0[j]) + w.y * bf2f(h1[j]);
    float* orow = out + (size_t)t * 1024 + c;
    *(float4*)orow       = *(float4*)&o[0];
    *(float4*)(orow + 4) = *(float4*)&o[4];
}

extern "C" void kernel_launch(void* const* d_in, const int* in_sizes, int n_in,
                              void* d_out, int out_size, void* d_ws, size_t ws_size,
                              hipStream_t stream)
{
    const float* x  = (const float*)d_in[0];
    const float* gw = (const float*)d_in[1];
    const float* gb = (const float*)d_in[2];
    const float* sg = (const float*)d_in[3];
    const float* su = (const float*)d_in[4];
    const float* sd = (const float*)d_in[5];
    const float* eg = (const float*)d_in[6];
    const float* eu = (const float*)d_in[7];
    const float* ed = (const float*)d_in[8];
    float* out = (float*)d_out;
    char* ws = (char*)d_ws;

    unsigned short* Wgu = (unsigned short*)(ws + OFF_WGU);
    unsigned short* Wd  = (unsigned short*)(ws + OFF_WD);
    unsigned short* xb  = (unsigned short*)(ws + OFF_XB);
    unsigned short* Hgu = (unsigned short*)(ws + OFF_HGU);
    unsigned short* H   = (unsigned short*)(ws + OFF_H);
    int*    tok   = (int*)(ws + OFF_TOK);
    int2*   rec   = (int2*)(ws + OFF_REC);
    float2* wrec  = (float2*)(ws + OFF_WREC);
    int*    counts= (int*)(ws + OFF_CNT);
    int*    bases = (int*)(ws + OFF_BASE);

    hipMemsetAsync(counts, 0, 4096, stream);
    k_transpose<<<dim3(16, 16, 51), 256, 0, stream>>>(eg, eu, ed, sg, su, sd, Wgu, Wd);
    k_xconv<<<4096, 256, 0, stream>>>(x, xb, tok);
    k_router<<<512, 512, 0, stream>>>(x, gw, gb, tok, rec, wrec, counts);
    k_prefix<<<1, 64, 0, stream>>>(counts, bases);
    k_gemm<0><<<dim3(8, 32, 17), 256, 0, stream>>>(xb, Wgu, tok, counts, bases, Hgu);
    k_silu<<<3072, 256, 0, stream>>>(Hgu, H);
    k_gemm<1><<<dim3(8, 32, 17), 256, 0, stream>>>(H, Wd, tok, counts, bases, Hgu);
    k_combine<<<2048, 256, 0, stream>>>(x, Hgu, rec, wrec, bases, out);
}

// Round 9
// 288.895 us; speedup vs baseline: 1.3830x; 1.0132x over previous
//
#include <hip/hip_runtime.h>
#include <stdint.h>

typedef __attribute__((ext_vector_type(8))) short short8;
typedef __attribute__((ext_vector_type(4))) float f32x4;

// ---- problem constants ----
#define TOKENS 4096
#define DDIM 1024
#define IDIM 512
#define NEXP 16
#define NEXP1 17
#define CSTRIDE 32    // counts padded: one counter per 128 B (atomic line ping-pong fix)
#define MAXMB 112     // max total m-blocks: 32 (shared) + max sum ceil(cnt/128) = 79 -> 111

// ---- workspace layout (bytes) ----
#define OFF_WGU   0ull           // 17*1024*1024*2   [e][n'(interleaved 2i+{g,u})][k] bf16
#define OFF_WD    35651584ull    // 17*1024*512*2    [e][n(D)][k(I)] bf16
#define OFF_XB    53477376ull    // 4096*1024*2      x in bf16
#define OFF_HGU   61865984ull    // 12288*1024*2     gemmB out (expert outputs per slot)
#define OFF_H     87031808ull    // 12288*512*2      silu(g)*u   (gemmA out, fused)
#define OFF_TOK   99614720ull    // 17*4096*4
#define OFF_REC   99893248ull    // 4096*8  per-token (e,p) records
#define OFF_WREC  99926016ull    // 4096*8  per-token (w0,w1)
#define OFF_CNT   100171776ull   // 17*128 padded counters (4096 B reserved)
#define OFF_BASE  100175872ull   // bases[18] then mbp[18] at +80B

__device__ __forceinline__ float bf2f(unsigned short u) {
    union { uint32_t i; float f; } v; v.i = ((uint32_t)u) << 16; return v.f;
}
__device__ __forceinline__ unsigned short f2bf(float f) {
    union { float f; uint32_t i; } v; v.f = f;
    uint32_t r = v.i + 0x7FFFu + ((v.i >> 16) & 1u);  // RNE
    return (unsigned short)(r >> 16);
}
// async 16B global->LDS (dest = wave-uniform base + lane*16)
__device__ __forceinline__ void cp16(const unsigned short* g, unsigned short* l) {
    __builtin_amdgcn_global_load_lds(
        (const __attribute__((address_space(1))) uint32_t*)g,
        (__attribute__((address_space(3))) uint32_t*)l, 16, 0, 0);
}

// ---- weight transpose + fp32->bf16. Wgu interleaved: col n' = 2*i + m (g/u pair
//      adjacent) so gemm<0> can silu-combine via lane shfl. Wd: [n(D)][k(I)]. ----
__global__ __launch_bounds__(256)
void k_transpose(const float* __restrict__ eg, const float* __restrict__ eu,
                 const float* __restrict__ ed, const float* __restrict__ sg,
                 const float* __restrict__ su, const float* __restrict__ sd,
                 unsigned short* __restrict__ Wgu, unsigned short* __restrict__ Wd)
{
    int z = blockIdx.z;
    int e = z / 3, m = z % 3;
    int R = (m == 2) ? 512 : 1024;   // src rows (k)
    int C = (m == 2) ? 1024 : 512;   // src cols (n)
    int r0 = blockIdx.y * 64, c0 = blockIdx.x * 64;
    if (r0 >= R || c0 >= C) return;
    const float* src;
    if (m == 0)      src = (e < 16) ? eg + (size_t)e * 524288 : sg;
    else if (m == 1) src = (e < 16) ? eu + (size_t)e * 524288 : su;
    else             src = (e < 16) ? ed + (size_t)e * 524288 : sd;

    __shared__ float tl[64 * 65];
    const int tid = threadIdx.x;

    {
        const int lr = tid >> 4;          // 0..15
        const int lc = (tid & 15) * 4;    // 0..60
        #pragma unroll
        for (int ps = 0; ps < 4; ++ps) {
            int r = ps * 16 + lr;
            float4 v = *(const float4*)(src + (size_t)(r0 + r) * C + (c0 + lc));
            float* d = &tl[r * 65 + lc];
            d[0] = v.x; d[1] = v.y; d[2] = v.z; d[3] = v.w;
        }
    }
    __syncthreads();

    {
        const int nl = tid >> 2;          // 0..63
        const int kc = (tid & 3) * 16;    // 0,16,32,48
        unsigned short ov[16];
        #pragma unroll
        for (int j = 0; j < 16; ++j)
            ov[j] = f2bf(tl[(kc + j) * 65 + nl]);
        int n = c0 + nl;
        int k = r0 + kc;
        unsigned short* dst;
        if (m < 2) dst = Wgu + (size_t)e * 1048576 + (size_t)(2 * n + m) * 1024 + k;
        else       dst = Wd  + (size_t)e * 524288  + (size_t)n * 512 + k;
        *(uint4*)dst       = *(uint4*)&ov[0];
        *(uint4*)(dst + 8) = *(uint4*)&ov[8];
    }
}

// ---- x -> bf16, fill shared-expert token list ----
__global__ void k_xconv(const float* __restrict__ x, unsigned short* __restrict__ xb,
                        int* __restrict__ tok)
{
    int i = blockIdx.x * 256 + threadIdx.x;   // 1048576 float4 groups, exact
    float4 v = ((const float4*)x)[i];
    ushort4 b;
    b.x = f2bf(v.x); b.y = f2bf(v.y); b.z = f2bf(v.z); b.w = f2bf(v.w);
    ((ushort4*)xb)[i] = b;
    if (i < TOKENS) tok[16 * 4096 + i] = i;
}

// ---- router: expert-phased LDS staging, fp64 accumulate, padded atomics ----
__global__ __launch_bounds__(512, 4)
void k_router(const float* __restrict__ x, const float* __restrict__ gw,
              const float* __restrict__ gb, int* __restrict__ tok,
              int2* __restrict__ rec, float2* __restrict__ wrec,
              int* __restrict__ counts)
{
    __shared__ float gws[1024 * 12];             // 49152 B

    const int t = blockIdx.x * 8 + (threadIdx.x >> 6);   // 512 blocks * 8 waves
    const int lane = threadIdx.x & 63;
    const float* xr = x + (size_t)t * DDIM;

    float xv[16];
    #pragma unroll
    for (int kk = 0; kk < 16; ++kk) xv[kk] = xr[kk * 64 + lane];

    float v[16];

    for (int p = 0; p < 2; ++p) {
        __syncthreads();
        #pragma unroll
        for (int c = 0; c < 4; ++c) {
            int idx = threadIdx.x + c * 512;     // 0..2047
            int k = idx >> 1;
            int h = (idx & 1) * 4;               // 0 or 4 floats
            float4 g4 = *(const float4*)(gw + k * 16 + p * 8 + h);
            *(float4*)&gws[k * 12 + h] = g4;
        }
        __syncthreads();

        double a[8];
        #pragma unroll
        for (int j = 0; j < 8; ++j) a[j] = 0.0;

        #pragma unroll
        for (int kk = 0; kk < 16; ++kk) {
            int kl = kk * 64 + lane;
            float4 gA = *(const float4*)&gws[kl * 12];
            float4 gB = *(const float4*)&gws[kl * 12 + 4];
            double xd = (double)xv[kk];
            a[0] += xd * (double)gA.x; a[1] += xd * (double)gA.y;
            a[2] += xd * (double)gA.z; a[3] += xd * (double)gA.w;
            a[4] += xd * (double)gB.x; a[5] += xd * (double)gB.y;
            a[6] += xd * (double)gB.z; a[7] += xd * (double)gB.w;
        }

        #pragma unroll
        for (int off = 32; off > 0; off >>= 1) {
            #pragma unroll
            for (int j = 0; j < 8; ++j)
                a[j] += __shfl_xor(a[j], off, 64);
        }

        #pragma unroll
        for (int j = 0; j < 8; ++j)
            v[p * 8 + j] = 1.0f / (1.0f + expf(-(float)(a[j] + (double)gb[p * 8 + j])));
    }

    if (lane == 0) {
        int i0 = 0;
        #pragma unroll
        for (int e = 1; e < 16; ++e) if (v[e] > v[i0]) i0 = e;
        int i1 = (i0 == 0) ? 1 : 0;
        #pragma unroll
        for (int e = 0; e < 16; ++e) if (e != i0 && e != i1 && v[e] > v[i1]) i1 = e;
        float s = v[i0] + v[i1];
        float w0 = v[i0] / s, w1 = v[i1] / s;
        int p0 = atomicAdd(&counts[i0 * CSTRIDE], 1);   // padded: 1 line per expert
        tok[i0 * 4096 + p0] = t;
        int p1 = atomicAdd(&counts[i1 * CSTRIDE], 1);
        tok[i1 * 4096 + p1] = t;
        rec[t]  = make_int2(i0 * 4096 + p0, i1 * 4096 + p1);
        wrec[t] = make_float2(w0, w1);
    }
}

// ---- prefix: slot bases + compacted m-block table ----
__global__ void k_prefix(int* counts, int* bases, int* mbp)
{
    if (threadIdx.x == 0 && blockIdx.x == 0) {
        counts[16 * CSTRIDE] = TOKENS;
        int a = 0, b = 0;
        for (int e = 0; e < NEXP1; ++e) {
            int c = counts[e * CSTRIDE];
            bases[e] = a; a += c;
            mbp[e] = b;  b += (c + 127) >> 7;
        }
        bases[17] = a;
        mbp[17] = b;
    }
}

// ---- grouped GEMM, 128x128 tile, 16x16x32 bf16 MFMA, 4 waves,
//      global_load_lds staging, compacted m-block grid ----
// MODE 0: A = xb gathered, K=1024, B = Wgu interleaved -> fused silu -> H (bf16)
// MODE 1: A = H (contiguous slots), K=512, B = Wd -> Hgu (bf16)
template <int MODE>
__global__ __launch_bounds__(256, 3)
void k_gemm(const unsigned short* __restrict__ Amat, const unsigned short* __restrict__ Bmat,
            const int* __restrict__ tok, const int* __restrict__ counts,
            const int* __restrict__ bases, const int* __restrict__ mbp,
            unsigned short* __restrict__ Out)
{
    constexpr int K = (MODE == 0) ? 1024 : 512;
    const int my = blockIdx.y;
    if (my >= mbp[17]) return;
    int e = 0;
    while (my >= mbp[e + 1]) ++e;          // <=17 scalar iterations
    const int cnt = counts[e * CSTRIDE];
    const int m0 = (my - mbp[e]) * 128;
    const int n0 = blockIdx.x * 128;
    const int base = bases[e];

    __shared__ unsigned short As[128 * 32];   // 8 KB, unpadded (global_load_lds layout)
    __shared__ unsigned short Bs[128 * 32];

    const int tid  = threadIdx.x;
    const int wave = tid >> 6;
    const int lane = tid & 63;
    const int lrow = lane >> 2;     // 0..15
    const int lseg = lane & 3;      // 16B segment within 32-elem k-slab

    unsigned short* a_dst0 = &As[wave * 1024];
    unsigned short* a_dst1 = &As[wave * 1024 + 512];
    unsigned short* b_dst0 = &Bs[wave * 1024];
    unsigned short* b_dst1 = &Bs[wave * 1024 + 512];

    int ar0 = m0 + wave * 32 + lrow;      if (ar0 > cnt - 1) ar0 = cnt - 1;
    int ar1 = m0 + wave * 32 + 16 + lrow; if (ar1 > cnt - 1) ar1 = cnt - 1;
    size_t ai0, ai1;
    if (MODE == 0) { ai0 = (size_t)tok[e * 4096 + ar0]; ai1 = (size_t)tok[e * 4096 + ar1]; }
    else           { ai0 = (size_t)(base + ar0);        ai1 = (size_t)(base + ar1); }
    const unsigned short* ag0 = Amat + ai0 * K + lseg * 8;
    const unsigned short* ag1 = Amat + ai1 * K + lseg * 8;
    const size_t eoff = (size_t)e * 1024 * K;
    const unsigned short* bg0 = Bmat + eoff + (size_t)(n0 + wave * 32 + lrow) * K + lseg * 8;
    const unsigned short* bg1 = Bmat + eoff + (size_t)(n0 + wave * 32 + 16 + lrow) * K + lseg * 8;

    const int wm = wave & 1, wn = wave >> 1;
    const int q = lane >> 4, mc = lane & 15;

    f32x4 acc[4][4];
    #pragma unroll
    for (int i = 0; i < 4; ++i)
        #pragma unroll
        for (int j = 0; j < 4; ++j) acc[i][j] = (f32x4){0.f, 0.f, 0.f, 0.f};

    for (int k0 = 0; k0 < K; k0 += 32) {
        __syncthreads();
        cp16(ag0 + k0, a_dst0);
        cp16(ag1 + k0, a_dst1);
        cp16(bg0 + k0, b_dst0);
        cp16(bg1 + k0, b_dst1);
        __syncthreads();
        short8 a[4], b[4];
        #pragma unroll
        for (int i = 0; i < 4; ++i)
            a[i] = *(const short8*)&As[(wm * 64 + i * 16 + mc) * 32 + q * 8];
        #pragma unroll
        for (int j = 0; j < 4; ++j)
            b[j] = *(const short8*)&Bs[(wn * 64 + j * 16 + mc) * 32 + q * 8];
        #pragma unroll
        for (int i = 0; i < 4; ++i)
            #pragma unroll
            for (int j = 0; j < 4; ++j)
                acc[i][j] = __builtin_amdgcn_mfma_f32_16x16x32_bf16(a[i], b[j], acc[i][j], 0, 0, 0);
    }

    // epilogue: C/D layout col=lane&15, row=(lane>>4)*4+reg  [m89-verified]
    #pragma unroll
    for (int i = 0; i < 4; ++i) {
        int lr = wm * 64 + i * 16 + q * 4;
        #pragma unroll
        for (int r = 0; r < 4; ++r) {
            int mrow = m0 + lr + r;
            if (mrow >= cnt) continue;
            #pragma unroll
            for (int j = 0; j < 4; ++j) {
                int gc = n0 + wn * 64 + j * 16 + mc;
                float val = acc[i][j][r];
                if (MODE == 0) {
                    // interleaved cols: even gc = gate(i=gc/2), odd = up. Pair via lane^1.
                    float other = __shfl_xor(val, 1, 64);
                    float g = (mc & 1) ? other : val;
                    float u = (mc & 1) ? val : other;
                    float h = g / (1.0f + __expf(-g)) * u;
                    if ((mc & 1) == 0)
                        Out[(size_t)(base + mrow) * 512 + (gc >> 1)] = f2bf(h);
                } else {
                    Out[(size_t)(base + mrow) * 1024 + gc] = f2bf(val);
                }
            }
        }
    }
}

// ---- out[t] = x[t] + Hs[shared] + w0*Hs[s0] + w1*Hs[s1] ----
__global__ void k_combine(const float* __restrict__ x, const unsigned short* __restrict__ Hs,
                          const int2* __restrict__ rec, const float2* __restrict__ wrec,
                          const int* __restrict__ bases, float* __restrict__ out)
{
    int t = blockIdx.x * 2 + (threadIdx.x >> 7);   // 2048 blocks * 2 tokens
    int c = (threadIdx.x & 127) * 8;
    int2 r = rec[t];
    float2 w = wrec[t];
    int s0 = bases[r.x >> 12] + (r.x & 4095);
    int s1 = bases[r.y >> 12] + (r.y & 4095);
    int ss = 8192 + t;                              // shared list base is always 8192

    unsigned short h0[8], h1[8], hs[8];
    *(uint4*)h0 = *(const uint4*)(Hs + (size_t)s0 * 1024 + c);
    *(uint4*)h1 = *(const uint4*)(Hs + (size_t)s1 * 1024 + c);
    *(uint4*)hs = *(const uint4*)(Hs + (size_t)ss * 1024 + c);
    const float* xr = x + (size_t)t * 1024 + c;
    float o[8];
    #pragma unroll
    for (int j = 0; j < 8; ++j)
        o[j] = xr[j] + bf2f(hs[j]) + w.x * bf2f(h0[j]) + w.y * bf2f(h1[j]);
    float* orow = out + (size_t)t * 1024 + c;
    *(float4*)orow       = *(float4*)&o[0];
    *(float4*)(orow + 4) = *(float4*)&o[4];
}

extern "C" void kernel_launch(void* const* d_in, const int* in_sizes, int n_in,
                              void* d_out, int out_size, void* d_ws, size_t ws_size,
                              hipStream_t stream)
{
    const float* x  = (const float*)d_in[0];
    const float* gw = (const float*)d_in[1];
    const float* gb = (const float*)d_in[2];
    const float* sg = (const float*)d_in[3];
    const float* su = (const float*)d_in[4];
    const float* sd = (const float*)d_in[5];
    const float* eg = (const float*)d_in[6];
    const float* eu = (const float*)d_in[7];
    const float* ed = (const float*)d_in[8];
    float* out = (float*)d_out;
    char* ws = (char*)d_ws;

    unsigned short* Wgu = (unsigned short*)(ws + OFF_WGU);
    unsigned short* Wd  = (unsigned short*)(ws + OFF_WD);
    unsigned short* xb  = (unsigned short*)(ws + OFF_XB);
    unsigned short* Hgu = (unsigned short*)(ws + OFF_HGU);
    unsigned short* H   = (unsigned short*)(ws + OFF_H);
    int*    tok   = (int*)(ws + OFF_TOK);
    int2*   rec   = (int2*)(ws + OFF_REC);
    float2* wrec  = (float2*)(ws + OFF_WREC);
    int*    counts= (int*)(ws + OFF_CNT);
    int*    bases = (int*)(ws + OFF_BASE);
    int*    mbp   = bases + 20;

    hipMemsetAsync(counts, 0, 4096, stream);
    k_transpose<<<dim3(16, 16, 51), 256, 0, stream>>>(eg, eu, ed, sg, su, sd, Wgu, Wd);
    k_xconv<<<4096, 256, 0, stream>>>(x, xb, tok);
    k_router<<<512, 512, 0, stream>>>(x, gw, gb, tok, rec, wrec, counts);
    k_prefix<<<1, 64, 0, stream>>>(counts, bases, mbp);
    k_gemm<0><<<dim3(8, MAXMB), 256, 0, stream>>>(xb, Wgu, tok, counts, bases, mbp, H);
    k_gemm<1><<<dim3(8, MAXMB), 256, 0, stream>>>(H, Wd, tok, counts, bases, mbp, Hgu);
    k_combine<<<2048, 256, 0, stream>>>(x, Hgu, rec, wrec, bases, out);
}

// Round 11
// 285.383 us; speedup vs baseline: 1.4000x; 1.0123x over previous
//
#include <hip/hip_runtime.h>
#include <stdint.h>

typedef __attribute__((ext_vector_type(8))) short short8;
typedef __attribute__((ext_vector_type(4))) float f32x4;

// ---- problem constants ----
#define TOKENS 4096
#define DDIM 1024
#define IDIM 512
#define NEXP 16
#define NEXP1 17
#define CSTRIDE 32    // counts padded: one counter per 128 B (atomic line ping-pong fix)
#define MAXMB 112     // max total m-blocks: 32 (shared) + sum ceil(cnt/128) <= 111

// ---- workspace layout (bytes) ----
#define OFF_WGU   0ull           // 17*1024*1024*2   [e][n'(interleaved 2i+{g,u})][k] bf16
#define OFF_WD    35651584ull    // 17*1024*512*2    [e][n(D)][k(I)] bf16
#define OFF_XB    53477376ull    // 4096*1024*2      x in bf16
#define OFF_HGU   61865984ull    // 12288*1024*2     gemmB out (expert outputs per slot)
#define OFF_H     87031808ull    // 12288*512*2      silu(g)*u   (gemmA out, fused)
#define OFF_TOK   99614720ull    // 17*4096*4
#define OFF_REC   99893248ull    // 4096*8  per-token (e,p) records
#define OFF_WREC  99926016ull    // 4096*8  per-token (w0,w1)
#define OFF_CNT   100171776ull   // 17*128 padded counters (4096 B reserved)
#define OFF_BASE  100175872ull   // bases[18] then mbp[18] at +80B

__device__ __forceinline__ float bf2f(unsigned short u) {
    union { uint32_t i; float f; } v; v.i = ((uint32_t)u) << 16; return v.f;
}
__device__ __forceinline__ unsigned short f2bf(float f) {
    union { float f; uint32_t i; } v; v.f = f;
    uint32_t r = v.i + 0x7FFFu + ((v.i >> 16) & 1u);  // RNE
    return (unsigned short)(r >> 16);
}
// async 16B global->LDS (dest = wave-uniform base + lane*16). imm offset ALWAYS 0 —
// non-zero imm offset on this instruction produced NaN (round 10): unverified HW path.
__device__ __forceinline__ void cp16(const unsigned short* g, unsigned short* l) {
    __builtin_amdgcn_global_load_lds(
        (const __attribute__((address_space(1))) uint32_t*)g,
        (__attribute__((address_space(3))) uint32_t*)l, 16, 0, 0);
}

// ---- weight transpose + fp32->bf16. Wgu interleaved: col n' = 2*i + m.
//      Store pass: 8-lane groups write full 128-B lines (fully coalesced). ----
__global__ __launch_bounds__(256)
void k_transpose(const float* __restrict__ eg, const float* __restrict__ eu,
                 const float* __restrict__ ed, const float* __restrict__ sg,
                 const float* __restrict__ su, const float* __restrict__ sd,
                 unsigned short* __restrict__ Wgu, unsigned short* __restrict__ Wd)
{
    int z = blockIdx.z;
    int e = z / 3, m = z % 3;
    int R = (m == 2) ? 512 : 1024;   // src rows (k)
    int C = (m == 2) ? 1024 : 512;   // src cols (n)
    int r0 = blockIdx.y * 64, c0 = blockIdx.x * 64;
    if (r0 >= R || c0 >= C) return;
    const float* src;
    if (m == 0)      src = (e < 16) ? eg + (size_t)e * 524288 : sg;
    else if (m == 1) src = (e < 16) ? eu + (size_t)e * 524288 : su;
    else             src = (e < 16) ? ed + (size_t)e * 524288 : sd;

    __shared__ float tl[64 * 65];
    const int tid = threadIdx.x;

    {
        const int lr = tid >> 4;          // 0..15
        const int lc = (tid & 15) * 4;    // 0..60
        #pragma unroll
        for (int ps = 0; ps < 4; ++ps) {
            int r = ps * 16 + lr;
            float4 v = *(const float4*)(src + (size_t)(r0 + r) * C + (c0 + lc));
            float* d = &tl[r * 65 + lc];
            d[0] = v.x; d[1] = v.y; d[2] = v.z; d[3] = v.w;
        }
    }
    __syncthreads();

    {
        const int w = tid >> 6, l = tid & 63;
        const int kb = (l & 7) * 8;       // k-chunk within tile (8 elems = 16 B)
        #pragma unroll
        for (int p = 0; p < 2; ++p) {
            int nl = p * 32 + w * 8 + (l >> 3);
            unsigned short ov[8];
            #pragma unroll
            for (int j = 0; j < 8; ++j)
                ov[j] = f2bf(tl[(kb + j) * 65 + nl]);
            int n = c0 + nl;
            int k = r0 + kb;
            unsigned short* dst;
            if (m < 2) dst = Wgu + (size_t)e * 1048576 + (size_t)(2 * n + m) * 1024 + k;
            else       dst = Wd  + (size_t)e * 524288  + (size_t)n * 512 + k;
            *(uint4*)dst = *(uint4*)ov;
        }
    }
}

// ---- x -> bf16, fill shared-expert token list ----
__global__ void k_xconv(const float* __restrict__ x, unsigned short* __restrict__ xb,
                        int* __restrict__ tok)
{
    int i = blockIdx.x * 256 + threadIdx.x;   // 1048576 float4 groups, exact
    float4 v = ((const float4*)x)[i];
    ushort4 b;
    b.x = f2bf(v.x); b.y = f2bf(v.y); b.z = f2bf(v.z); b.w = f2bf(v.w);
    ((ushort4*)xb)[i] = b;
    if (i < TOKENS) tok[16 * 4096 + i] = i;
}

// ---- router: expert-phased LDS staging, fp64 accumulate, padded atomics ----
__global__ __launch_bounds__(512, 4)
void k_router(const float* __restrict__ x, const float* __restrict__ gw,
              const float* __restrict__ gb, int* __restrict__ tok,
              int2* __restrict__ rec, float2* __restrict__ wrec,
              int* __restrict__ counts)
{
    __shared__ float gws[1024 * 12];             // 49152 B

    const int t = blockIdx.x * 8 + (threadIdx.x >> 6);   // 512 blocks * 8 waves
    const int lane = threadIdx.x & 63;
    const float* xr = x + (size_t)t * DDIM;

    float xv[16];
    #pragma unroll
    for (int kk = 0; kk < 16; ++kk) xv[kk] = xr[kk * 64 + lane];

    float v[16];

    for (int p = 0; p < 2; ++p) {
        __syncthreads();
        #pragma unroll
        for (int c = 0; c < 4; ++c) {
            int idx = threadIdx.x + c * 512;     // 0..2047
            int k = idx >> 1;
            int h = (idx & 1) * 4;               // 0 or 4 floats
            float4 g4 = *(const float4*)(gw + k * 16 + p * 8 + h);
            *(float4*)&gws[k * 12 + h] = g4;
        }
        __syncthreads();

        double a[8];
        #pragma unroll
        for (int j = 0; j < 8; ++j) a[j] = 0.0;

        #pragma unroll
        for (int kk = 0; kk < 16; ++kk) {
            int kl = kk * 64 + lane;
            float4 gA = *(const float4*)&gws[kl * 12];
            float4 gB = *(const float4*)&gws[kl * 12 + 4];
            double xd = (double)xv[kk];
            a[0] += xd * (double)gA.x; a[1] += xd * (double)gA.y;
            a[2] += xd * (double)gA.z; a[3] += xd * (double)gA.w;
            a[4] += xd * (double)gB.x; a[5] += xd * (double)gB.y;
            a[6] += xd * (double)gB.z; a[7] += xd * (double)gB.w;
        }

        #pragma unroll
        for (int off = 32; off > 0; off >>= 1) {
            #pragma unroll
            for (int j = 0; j < 8; ++j)
                a[j] += __shfl_xor(a[j], off, 64);
        }

        #pragma unroll
        for (int j = 0; j < 8; ++j)
            v[p * 8 + j] = 1.0f / (1.0f + expf(-(float)(a[j] + (double)gb[p * 8 + j])));
    }

    if (lane == 0) {
        int i0 = 0;
        #pragma unroll
        for (int e = 1; e < 16; ++e) if (v[e] > v[i0]) i0 = e;
        int i1 = (i0 == 0) ? 1 : 0;
        #pragma unroll
        for (int e = 0; e < 16; ++e) if (e != i0 && e != i1 && v[e] > v[i1]) i1 = e;
        float s = v[i0] + v[i1];
        float w0 = v[i0] / s, w1 = v[i1] / s;
        int p0 = atomicAdd(&counts[i0 * CSTRIDE], 1);   // padded: 1 line per expert
        tok[i0 * 4096 + p0] = t;
        int p1 = atomicAdd(&counts[i1 * CSTRIDE], 1);
        tok[i1 * 4096 + p1] = t;
        rec[t]  = make_int2(i0 * 4096 + p0, i1 * 4096 + p1);
        wrec[t] = make_float2(w0, w1);
    }
}

// ---- prefix: slot bases + compacted m-block table ----
__global__ void k_prefix(int* counts, int* bases, int* mbp)
{
    if (threadIdx.x == 0 && blockIdx.x == 0) {
        counts[16 * CSTRIDE] = TOKENS;
        int a = 0, b = 0;
        for (int e = 0; e < NEXP1; ++e) {
            int c = counts[e * CSTRIDE];
            bases[e] = a; a += c;
            mbp[e] = b;  b += (c + 127) >> 7;
        }
        bases[17] = a;
        mbp[17] = b;
    }
}

// ---- grouped GEMM, 128x128 tile, BK=64 (32 MFMA per barrier pair),
//      global_load_lds staging into 4x8KB half-buffers, all imm offsets 0 ----
// MODE 0: A = xb gathered, K=1024, B = Wgu interleaved -> fused silu -> H (bf16)
// MODE 1: A = H (contiguous slots), K=512, B = Wd -> Hgu (bf16)
template <int MODE>
__global__ __launch_bounds__(256, 3)
void k_gemm(const unsigned short* __restrict__ Amat, const unsigned short* __restrict__ Bmat,
            const int* __restrict__ tok, const int* __restrict__ counts,
            const int* __restrict__ bases, const int* __restrict__ mbp,
            unsigned short* __restrict__ Out)
{
    constexpr int K = (MODE == 0) ? 1024 : 512;
    const int my = blockIdx.y;
    if (my >= mbp[17]) return;
    int e = 0;
    while (my >= mbp[e + 1]) ++e;          // <=17 scalar iterations
    const int cnt = counts[e * CSTRIDE];
    const int m0 = (my - mbp[e]) * 128;
    const int n0 = blockIdx.x * 128;
    const int base = bases[e];

    __shared__ unsigned short As0[128 * 32];   // k-half 0 (8 KB each, 64-B rows)
    __shared__ unsigned short As1[128 * 32];   // k-half 1
    __shared__ unsigned short Bs0[128 * 32];
    __shared__ unsigned short Bs1[128 * 32];

    const int tid  = threadIdx.x;
    const int wave = tid >> 6;
    const int lane = tid & 63;
    const int lrow = lane >> 2;     // 0..15
    const int lseg = lane & 3;      // 16B segment within 32-elem k-half

    unsigned short* a0d0 = &As0[wave * 1024];
    unsigned short* a0d1 = &As0[wave * 1024 + 512];
    unsigned short* a1d0 = &As1[wave * 1024];
    unsigned short* a1d1 = &As1[wave * 1024 + 512];
    unsigned short* b0d0 = &Bs0[wave * 1024];
    unsigned short* b0d1 = &Bs0[wave * 1024 + 512];
    unsigned short* b1d0 = &Bs1[wave * 1024];
    unsigned short* b1d1 = &Bs1[wave * 1024 + 512];

    int ar0 = m0 + wave * 32 + lrow;      if (ar0 > cnt - 1) ar0 = cnt - 1;
    int ar1 = m0 + wave * 32 + 16 + lrow; if (ar1 > cnt - 1) ar1 = cnt - 1;
    size_t ai0, ai1;
    if (MODE == 0) { ai0 = (size_t)tok[e * 4096 + ar0]; ai1 = (size_t)tok[e * 4096 + ar1]; }
    else           { ai0 = (size_t)(base + ar0);        ai1 = (size_t)(base + ar1); }
    const unsigned short* ag0 = Amat + ai0 * K + lseg * 8;
    const unsigned short* ag1 = Amat + ai1 * K + lseg * 8;
    const size_t eoff = (size_t)e * 1024 * K;
    const unsigned short* bg0 = Bmat + eoff + (size_t)(n0 + wave * 32 + lrow) * K + lseg * 8;
    const unsigned short* bg1 = Bmat + eoff + (size_t)(n0 + wave * 32 + 16 + lrow) * K + lseg * 8;

    const int wm = wave & 1, wn = wave >> 1;
    const int q = lane >> 4, mc = lane & 15;

    f32x4 acc[4][4];
    #pragma unroll
    for (int i = 0; i < 4; ++i)
        #pragma unroll
        for (int j = 0; j < 4; ++j) acc[i][j] = (f32x4){0.f, 0.f, 0.f, 0.f};

    for (int k0 = 0; k0 < K; k0 += 64) {
        __syncthreads();
        cp16(ag0 + k0,      a0d0);       // k-half 0 (elems k0+0..31)
        cp16(ag0 + k0 + 32, a1d0);       // k-half 1 (elems k0+32..63)
        cp16(ag1 + k0,      a0d1);
        cp16(ag1 + k0 + 32, a1d1);
        cp16(bg0 + k0,      b0d0);
        cp16(bg0 + k0 + 32, b1d0);
        cp16(bg1 + k0,      b0d1);
        cp16(bg1 + k0 + 32, b1d1);
        __syncthreads();
        short8 a0[4], b0[4], a1[4], b1[4];
        #pragma unroll
        for (int i = 0; i < 4; ++i) {
            a0[i] = *(const short8*)&As0[(wm * 64 + i * 16 + mc) * 32 + q * 8];
            a1[i] = *(const short8*)&As1[(wm * 64 + i * 16 + mc) * 32 + q * 8];
        }
        #pragma unroll
        for (int j = 0; j < 4; ++j) {
            b0[j] = *(const short8*)&Bs0[(wn * 64 + j * 16 + mc) * 32 + q * 8];
            b1[j] = *(const short8*)&Bs1[(wn * 64 + j * 16 + mc) * 32 + q * 8];
        }
        #pragma unroll
        for (int i = 0; i < 4; ++i)
            #pragma unroll
            for (int j = 0; j < 4; ++j)
                acc[i][j] = __builtin_amdgcn_mfma_f32_16x16x32_bf16(a0[i], b0[j], acc[i][j], 0, 0, 0);
        #pragma unroll
        for (int i = 0; i < 4; ++i)
            #pragma unroll
            for (int j = 0; j < 4; ++j)
                acc[i][j] = __builtin_amdgcn_mfma_f32_16x16x32_bf16(a1[i], b1[j], acc[i][j], 0, 0, 0);
    }

    // epilogue: C/D layout col=lane&15, row=(lane>>4)*4+reg  [m89-verified]
    #pragma unroll
    for (int i = 0; i < 4; ++i) {
        int lr = wm * 64 + i * 16 + q * 4;
        #pragma unroll
        for (int r = 0; r < 4; ++r) {
            int mrow = m0 + lr + r;
            if (mrow >= cnt) continue;
            #pragma unroll
            for (int j = 0; j < 4; ++j) {
                int gc = n0 + wn * 64 + j * 16 + mc;
                float val = acc[i][j][r];
                if (MODE == 0) {
                    // interleaved cols: even gc = gate(i=gc/2), odd = up. Pair via lane^1.
                    float other = __shfl_xor(val, 1, 64);
                    float g = (mc & 1) ? other : val;
                    float u = (mc & 1) ? val : other;
                    float h = g / (1.0f + __expf(-g)) * u;
                    if ((mc & 1) == 0)
                        Out[(size_t)(base + mrow) * 512 + (gc >> 1)] = f2bf(h);
                } else {
                    Out[(size_t)(base + mrow) * 1024 + gc] = f2bf(val);
                }
            }
        }
    }
}

// ---- out[t] = x[t] + Hs[shared] + w0*Hs[s0] + w1*Hs[s1] ----
__global__ void k_combine(const float* __restrict__ x, const unsigned short* __restrict__ Hs,
                          const int2* __restrict__ rec, const float2* __restrict__ wrec,
                          const int* __restrict__ bases, float* __restrict__ out)
{
    int t = blockIdx.x * 2 + (threadIdx.x >> 7);   // 2048 blocks * 2 tokens
    int c = (threadIdx.x & 127) * 8;
    int2 r = rec[t];
    float2 w = wrec[t];
    int s0 = bases[r.x >> 12] + (r.x & 4095);
    int s1 = bases[r.y >> 12] + (r.y & 4095);
    int ss = 8192 + t;                              // shared list base is always 8192

    unsigned short h0[8], h1[8], hs[8];
    *(uint4*)h0 = *(const uint4*)(Hs + (size_t)s0 * 1024 + c);
    *(uint4*)h1 = *(const uint4*)(Hs + (size_t)s1 * 1024 + c);
    *(uint4*)hs = *(const uint4*)(Hs + (size_t)ss * 1024 + c);
    const float* xr = x + (size_t)t * 1024 + c;
    float o[8];
    #pragma unroll
    for (int j = 0; j < 8; ++j)
        o[j] = xr[j] + bf2f(hs[j]) + w.x * bf2f(h0[j]) + w.y * bf2f(h1[j]);
    float* orow = out + (size_t)t * 1024 + c;
    *(float4*)orow       = *(float4*)&o[0];
    *(float4*)(orow + 4) = *(float4*)&o[4];
}

extern "C" void kernel_launch(void* const* d_in, const int* in_sizes, int n_in,
                              void* d_out, int out_size, void* d_ws, size_t ws_size,
                              hipStream_t stream)
{
    const float* x  = (const float*)d_in[0];
    const float* gw = (const float*)d_in[1];
    const float* gb = (const float*)d_in[2];
    const float* sg = (const float*)d_in[3];
    const float* su = (const float*)d_in[4];
    const float* sd = (const float*)d_in[5];
    const float* eg = (const float*)d_in[6];
    const float* eu = (const float*)d_in[7];
    const float* ed = (const float*)d_in[8];
    float* out = (float*)d_out;
    char* ws = (char*)d_ws;

    unsigned short* Wgu = (unsigned short*)(ws + OFF_WGU);
    unsigned short* Wd  = (unsigned short*)(ws + OFF_WD);
    unsigned short* xb  = (unsigned short*)(ws + OFF_XB);
    unsigned short* Hgu = (unsigned short*)(ws + OFF_HGU);
    unsigned short* H   = (unsigned short*)(ws + OFF_H);
    int*    tok   = (int*)(ws + OFF_TOK);
    int2*   rec   = (int2*)(ws + OFF_REC);
    float2* wrec  = (float2*)(ws + OFF_WREC);
    int*    counts= (int*)(ws + OFF_CNT);
    int*    bases = (int*)(ws + OFF_BASE);
    int*    mbp   = bases + 20;

    hipMemsetAsync(counts, 0, 4096, stream);
    k_transpose<<<dim3(16, 16, 51), 256, 0, stream>>>(eg, eu, ed, sg, su, sd, Wgu, Wd);
    k_xconv<<<4096, 256, 0, stream>>>(x, xb, tok);
    k_router<<<512, 512, 0, stream>>>(x, gw, gb, tok, rec, wrec, counts);
    k_prefix<<<1, 64, 0, stream>>>(counts, bases, mbp);
    k_gemm<0><<<dim3(8, MAXMB), 256, 0, stream>>>(xb, Wgu, tok, counts, bases, mbp, H);
    k_gemm<1><<<dim3(8, MAXMB), 256, 0, stream>>>(H, Wd, tok, counts, bases, mbp, Hgu);
    k_combine<<<2048, 256, 0, stream>>>(x, Hgu, rec, wrec, bases, out);
}